// Round 2
// baseline (614.681 us; speedup 1.0000x reference)
//
#include <hip/hip_runtime.h>

#define BB 32
#define SS 512
#define EE 512
#define NHH 2
#define HDD 256
#define E3 1536
#define NT 24
#define MR (BB*SS)   // 16384
#define NCH 16       // forward scan chunks (chunk 0 serial, 1..15 parallel)

typedef _Float16 half8  __attribute__((ext_vector_type(8)));
typedef _Float16 half4v __attribute__((ext_vector_type(4)));
typedef float    f32x4  __attribute__((ext_vector_type(4)));

// scalar (SGPR) lane broadcast — index MUST be wave-uniform.
__device__ __forceinline__ float rl(float v, int l) {
    return __int_as_float(__builtin_amdgcn_readlane(__float_as_int(v), l));
}

// =====================================================================
// fp32-accurate GEMM via fp16 3-product MFMA split (Ootomo).
// 128x128 block tile, 256 thr = 2x2 waves, 4x4 tiles of 16x16x32 f16.
// BN=0: B is row-major N x K (B^T form). BN=1: B is row-major K x N (V).
// =====================================================================
template<int BN>
__global__ __launch_bounds__(256) void mfma_gemm(
    const float* __restrict__ A, int lda, long sAhi, long sAlo, int zA,
    const float* __restrict__ B, int ldb, long sBhi, long sBlo, int zB,
    const float* __restrict__ bias,
    float* __restrict__ C, int ldc, long sChi, long sClo, int zC,
    int K, int relu)
{
    __shared__ __align__(16) _Float16 sAh[8*640];
    __shared__ __align__(16) _Float16 sAl[8*640];
    __shared__ __align__(16) _Float16 sBh[8*640];
    __shared__ __align__(16) _Float16 sBl[8*640];

    const int t = threadIdx.x;
    const int z = blockIdx.z;
    const int za = zA + z, zb = zB + z, zc = zC + z;
    const float* Ab = A + (size_t)(za>>1)*sAhi + (size_t)(za&1)*sAlo
                        + (size_t)blockIdx.y*128*lda;
    const float* Bb = B + (size_t)(zb>>1)*sBhi + (size_t)(zb&1)*sBlo
                        + (BN ? (size_t)blockIdx.x*128
                              : (size_t)blockIdx.x*128*ldb);

    const int wv = t >> 6, lane = t & 63;
    const int wm = wv >> 1, wn = wv & 1;
    const int lm = lane & 15, lq = lane >> 4;

    f32x4 acc[4][4];
#pragma unroll
    for (int i = 0; i < 4; ++i)
#pragma unroll
        for (int j = 0; j < 4; ++j) acc[i][j] = (f32x4){0.f,0.f,0.f,0.f};

    const int r8  = t >> 3;         // 0..31 (staging row base)
    const int kc  = (t & 7) * 4;    // 0..28 (staging k chunk)
    const int bnk = (t >> 7) * 16;  // BN staging: k half
    const int bnn = t & 127;        // BN staging: n

    for (int k0 = 0; k0 < K; k0 += 32) {
        float4 ga[4], gb[4]; float gv[16];
#pragma unroll
        for (int i = 0; i < 4; ++i)
            ga[i] = *(const float4*)(Ab + (size_t)(r8 + 32*i)*lda + k0 + kc);
        if (BN) {
#pragma unroll
            for (int i = 0; i < 16; ++i)
                gv[i] = Bb[(size_t)(k0 + bnk + i)*ldb + bnn];
        } else {
#pragma unroll
            for (int i = 0; i < 4; ++i)
                gb[i] = *(const float4*)(Bb + (size_t)(r8 + 32*i)*ldb + k0 + kc);
        }
        __syncthreads();   // previous iteration's fragment reads complete
#pragma unroll
        for (int i = 0; i < 4; ++i) {
            const int row  = r8 + 32*i;
            const int base = (row >> 4)*640 + (row & 15)*40 + kc;
            float4 a = ga[i];
            _Float16 h0 = (_Float16)a.x, h1 = (_Float16)a.y,
                     h2 = (_Float16)a.z, h3 = (_Float16)a.w;
            _Float16 l0 = (_Float16)(a.x - (float)h0),
                     l1 = (_Float16)(a.y - (float)h1),
                     l2 = (_Float16)(a.z - (float)h2),
                     l3 = (_Float16)(a.w - (float)h3);
            *(half4v*)&sAh[base] = (half4v){h0,h1,h2,h3};
            *(half4v*)&sAl[base] = (half4v){l0,l1,l2,l3};
        }
        if (BN) {
#pragma unroll
            for (int i = 0; i < 16; ++i) {
                const int k = bnk + i;
                float v = gv[i];
                _Float16 h = (_Float16)v;
                _Float16 l = (_Float16)(v - (float)h);
                const int base = (bnn >> 4)*640 + (bnn & 15)*40 + k;
                sBh[base] = h;
                sBl[base] = l;
            }
        } else {
#pragma unroll
            for (int i = 0; i < 4; ++i) {
                const int row  = r8 + 32*i;
                const int base = (row >> 4)*640 + (row & 15)*40 + kc;
                float4 b = gb[i];
                _Float16 h0 = (_Float16)b.x, h1 = (_Float16)b.y,
                         h2 = (_Float16)b.z, h3 = (_Float16)b.w;
                _Float16 l0 = (_Float16)(b.x - (float)h0),
                         l1 = (_Float16)(b.y - (float)h1),
                         l2 = (_Float16)(b.z - (float)h2),
                         l3 = (_Float16)(b.w - (float)h3);
                *(half4v*)&sBh[base] = (half4v){h0,h1,h2,h3};
                *(half4v*)&sBl[base] = (half4v){l0,l1,l2,l3};
            }
        }
        __syncthreads();

        half8 bhf[4], blf[4];
#pragma unroll
        for (int j = 0; j < 4; ++j) {
            const int tb = (wn*4 + j)*640 + lm*40 + lq*8;
            bhf[j] = *(const half8*)&sBh[tb];
            blf[j] = *(const half8*)&sBl[tb];
        }
#pragma unroll
        for (int i = 0; i < 4; ++i) {
            const int ta = (wm*4 + i)*640 + lm*40 + lq*8;
            half8 ah = *(const half8*)&sAh[ta];
            half8 al = *(const half8*)&sAl[ta];
#pragma unroll
            for (int j = 0; j < 4; ++j) {
                acc[i][j] = __builtin_amdgcn_mfma_f32_16x16x32_f16(ah, bhf[j], acc[i][j], 0, 0, 0);
                acc[i][j] = __builtin_amdgcn_mfma_f32_16x16x32_f16(al, bhf[j], acc[i][j], 0, 0, 0);
                acc[i][j] = __builtin_amdgcn_mfma_f32_16x16x32_f16(ah, blf[j], acc[i][j], 0, 0, 0);
            }
        }
    }

    // epilogue: C/D layout col = lane&15, row = quad*4 + reg
    float* Cb = C + (size_t)(zc>>1)*sChi + (size_t)(zc&1)*sClo;
#pragma unroll
    for (int j = 0; j < 4; ++j) {
        const int col = blockIdx.x*128 + (wn*4 + j)*16 + lm;
        const float bj = bias ? bias[col] : 0.f;
#pragma unroll
        for (int i = 0; i < 4; ++i) {
            const int row0 = blockIdx.y*128 + (wm*4 + i)*16 + lq*4;
#pragma unroll
            for (int r = 0; r < 4; ++r) {
                float v = acc[i][j][r] + bj;
                if (relu) v = fmaxf(v, 0.f);
                Cb[(size_t)(row0 + r)*ldc + col] = v;
            }
        }
    }
}

// =====================================================================
// Row softmax over scores (in place, fully normalized).
// =====================================================================
__global__ __launch_bounds__(256) void softmax_rows(float* __restrict__ scores)
{
    const int w    = threadIdx.x >> 6;
    const int lane = threadIdx.x & 63;
    const size_t row = (size_t)blockIdx.x * 4 + w;
    float* p = scores + row * SS + lane * 8;
    float4 v0 = *(float4*)(p);
    float4 v1 = *(float4*)(p + 4);
    const float scale = 0.0625f;
    float m = fmaxf(fmaxf(fmaxf(v0.x, v0.y), fmaxf(v0.z, v0.w)),
                    fmaxf(fmaxf(v1.x, v1.y), fmaxf(v1.z, v1.w)));
#pragma unroll
    for (int off = 32; off >= 1; off >>= 1) m = fmaxf(m, __shfl_xor(m, off));
    v0.x = __expf((v0.x - m) * scale); v0.y = __expf((v0.y - m) * scale);
    v0.z = __expf((v0.z - m) * scale); v0.w = __expf((v0.w - m) * scale);
    v1.x = __expf((v1.x - m) * scale); v1.y = __expf((v1.y - m) * scale);
    v1.z = __expf((v1.z - m) * scale); v1.w = __expf((v1.w - m) * scale);
    float sum = v0.x + v0.y + v0.z + v0.w + v1.x + v1.y + v1.z + v1.w;
#pragma unroll
    for (int off = 32; off >= 1; off >>= 1) sum += __shfl_xor(sum, off);
    float inv = 1.f / sum;
    v0.x *= inv; v0.y *= inv; v0.z *= inv; v0.w *= inv;
    v1.x *= inv; v1.y *= inv; v1.z *= inv; v1.w *= inv;
    *(float4*)(p)     = v0;
    *(float4*)(p + 4) = v1;
}

// =====================================================================
// CRF emissions: fc[row][j] = dot(dec[row], crf_w[j]) + crf_b[j]
// =====================================================================
__global__ __launch_bounds__(192) void fc_crf_kernel(
    const float* __restrict__ dec, const float* __restrict__ W,
    const float* __restrict__ bias, float* __restrict__ out)
{
    __shared__ __align__(16) float Ws[NT][516];
    for (int i = threadIdx.x; i < NT*128; i += 192) {
        int j = i >> 7, c = (i & 127) * 4;
        *(float4*)&Ws[j][c] = *(const float4*)(W + (size_t)j*EE + c);
    }
    __syncthreads();
    const int t = threadIdx.x;
    const int rloc = t / NT;
    const int j = t - rloc * NT;
    const int row = blockIdx.x * 8 + rloc;
    const float4* a = (const float4*)(dec + (size_t)row * EE);
    float acc = 0.f;
#pragma unroll 4
    for (int i = 0; i < 128; ++i) {
        float4 x = a[i];
        float4 y = *(const float4*)&Ws[j][i*4];
        acc += x.x*y.x + x.y*y.y + x.z*y.z + x.w*y.w;
    }
    out[(size_t)row * NT + j] = acc + bias[j];
}

// =====================================================================
// Round-12: chunk-parallel forward scan, phase A (the parallel part).
// The log-normalizer recursion is an associative scan in the LSE
// semiring.  Chunks c=1..15 (32 steps each) compute their 24x24
// transfer matrix M_c[i][j] = alpha_after_chunk[j] given one-hot entry
// state i, by running the *same* per-step recursion as the serial code
// from a one-hot start.  One wave per (batch, chunk, entry column):
// 32*15*24 = 11520 waves — fully parallel, hides all latency with TLP.
// Serial depth of forward drops 511 -> 31 + 15 combines (in crf_seg).
// den reassociates (~1e-6 rel) — only affects the single llh scalar.
// =====================================================================
__global__ __launch_bounds__(256) void fwd_chunks_kernel(
    const float* __restrict__ fc, const float* __restrict__ trans,
    float* __restrict__ Mws)
{
    const int w    = blockIdx.x * 4 + (threadIdx.x >> 6);   // 0..11519
    const int lane = threadIdx.x & 63;
    const int b    = w / ((NCH-1)*NT);
    const int r    = w - b * (NCH-1)*NT;
    const int c    = 1 + r / NT;                            // chunk 1..15
    const int i0   = __builtin_amdgcn_readfirstlane(r - (r / NT) * NT);
    const int j    = (lane < NT) ? lane : 0;
    const float* fcb = fc + (size_t)b * SS * NT;

    float etr[NT];
#pragma unroll
    for (int i = 0; i < NT; ++i) etr[i] = __expf(trans[i*NT + j]);

    // one-hot (log-domain) start: 0 at entry state i0, -inf elsewhere
    float sc = (lane == i0) ? 0.f : -1e30f;
    const int s0 = 32 * c;
    float em_next = fcb[(size_t)s0 * NT + j];
    for (int s = s0; s < s0 + 32; ++s) {
        float em = em_next;
        int snx = (s + 1 < SS) ? s + 1 : s;
        em_next = fcb[(size_t)snx * NT + j];
        // stabilizer: entry lane's own alpha (finite from the start;
        // -1e30 - m underflows cleanly to exp -> 0)
        const float m  = rl(sc, i0);
        const float eo = __expf(sc - m);
        float a0 = 0.f, a1 = 0.f, a2 = 0.f, a3 = 0.f;
#pragma unroll
        for (int i = 0; i < NT; i += 4) {
            a0 = fmaf(rl(eo, i+0), etr[i+0], a0);
            a1 = fmaf(rl(eo, i+1), etr[i+1], a1);
            a2 = fmaf(rl(eo, i+2), etr[i+2], a2);
            a3 = fmaf(rl(eo, i+3), etr[i+3], a3);
        }
        sc = m + __logf((a0 + a1) + (a2 + a3)) + em;
    }
    if (lane < NT)
        Mws[(((size_t)b * (NCH-1) + (c-1)) * NT + i0) * NT + lane] = sc;
}

// =====================================================================
// CRF + seg, 64-thread blocks.
// blocks 0..95: CRF tasks (forward-combine / viterbi / numerator).
// blocks >= 96: seg head, 8 rows per block.
// Round-12 role 0: 31 exact serial steps (chunk 0) then 15 stabilized
// LSE matrix-vector combines using fwd_chunks' transfer matrices
// (staged in LDS).  Viterbi/backtrack/numerator/seg: bit-exact,
// unchanged from round 11.
// =====================================================================
__global__ __launch_bounds__(64, 1) void crf_seg_kernel(
    const float* __restrict__ fc, const int* __restrict__ labels,
    const float* __restrict__ start_t, const float* __restrict__ end_t,
    const float* __restrict__ trans, const float* __restrict__ dec,
    const float* __restrict__ ent_w, const float* __restrict__ ent_b,
    float* __restrict__ num, float* __restrict__ den,
    float* __restrict__ crf_out, float* __restrict__ segout,
    const float* __restrict__ Mws)
{
    __shared__ __align__(16) float fc_lds[SS*NT];     // 48 KB (role0: em chunk + M; viterbi: em, then C1 scratch)
    __shared__ unsigned char hist[(SS-1)*NT];         // 12 KB  (C0)
    __shared__ unsigned char anchor[SS];              // backtrack anchors

    const int blk  = blockIdx.x;
    const int lane = threadIdx.x;

    if (blk >= 96) {
        // ---------------- segmentation head: 8 rows per block -----------
        const int row0 = (blk - 96) * 8;
        const float4* w0 = (const float4*)(ent_w);
        const float4* w1 = (const float4*)(ent_w + EE);
        const int i0 = lane * 2, i1 = lane * 2 + 1;
        const float4 u0 = w0[i0], u1 = w0[i1];
        const float4 q0 = w1[i0], q1 = w1[i1];
        const float eb0 = ent_b[0], eb1 = ent_b[1];
#pragma unroll 2
        for (int r = 0; r < 8; ++r) {
            const int row = row0 + r;
            const float4* a = (const float4*)(dec + (size_t)row * EE);
            float acc0 = 0.f, acc1 = 0.f;
            {
                float4 x = a[i0];
                acc0 += x.x*u0.x + x.y*u0.y + x.z*u0.z + x.w*u0.w;
                acc1 += x.x*q0.x + x.y*q0.y + x.z*q0.z + x.w*q0.w;
            }
            {
                float4 x = a[i1];
                acc0 += x.x*u1.x + x.y*u1.y + x.z*u1.z + x.w*u1.w;
                acc1 += x.x*q1.x + x.y*q1.y + x.z*q1.z + x.w*q1.w;
            }
#pragma unroll
            for (int off = 32; off >= 1; off >>= 1) {
                acc0 += __shfl_xor(acc0, off);
                acc1 += __shfl_xor(acc1, off);
            }
            if (lane == 0) {
                float l0 = acc0 + eb0;
                float l1 = acc1 + eb1;
                float m  = fmaxf(l0, l1);
                float lse = m + __logf(__expf(l0 - m) + __expf(l1 - m));
                segout[(size_t)row*2 + 0] = l0 - lse;
                segout[(size_t)row*2 + 1] = l1 - lse;
            }
        }
        return;
    }

    const int role = blk >> 5;          // 0=forward, 1=viterbi, 2=numerator
    const int b    = blk & 31;
    const float* fcb = fc + (size_t)b * SS * NT;

    if (role == 2) {
        // ---- numerator (one pass, already parallel; no LDS needed) ----
        float acc = 0.f;
        for (int s = 1 + lane; s < SS; s += 64) {
            int prev = labels[b*SS + s - 1];
            int cur  = labels[b*SS + s];
            acc += trans[prev*NT + cur] + fcb[(size_t)s*NT + cur];
        }
        if (lane == 0) {
            int l0 = labels[b*SS];
            acc += start_t[l0] + fcb[l0] + end_t[labels[b*SS + SS - 1]];
        }
#pragma unroll
        for (int off = 32; off >= 1; off >>= 1) acc += __shfl_xor(acc, off);
        if (lane == 0) num[b] = acc;
        return;
    }

    // lane j<24 owns destination tag j
    const int j = (lane < NT) ? lane : 0;

    if (role == 0) {
        // ---- forward phase B: chunk-0 serial + 15 transfer combines ----
        // stage chunk-0 emissions (positions 0..31): 768 floats
        for (int idx = lane*4; idx < 32*NT; idx += 256)
            *(float4*)&fc_lds[idx] = *(const float4*)(fcb + idx);
        // stage this batch's transfer matrices: 15*24*24 = 8640 floats
        const float* Mb = Mws + (size_t)b * (NCH-1)*NT*NT;
        for (int idx = lane*4; idx < (NCH-1)*NT*NT; idx += 256)
            *(float4*)&fc_lds[1024 + idx] = *(const float4*)(Mb + idx);
        __syncthreads();

        float sc = start_t[j] + fc_lds[j];
        float etr[NT];
#pragma unroll
        for (int i = 0; i < NT; ++i) etr[i] = __expf(trans[i*NT + j]);
        // chunk 0: exact serial recursion, s = 1..31
        float em_next = fc_lds[NT + j];
        for (int s = 1; s < 32; ++s) {
            float em = em_next;
            int snx = (s + 1 < 32) ? s + 1 : s;
            em_next = fc_lds[snx * NT + j];
            const float m  = __builtin_amdgcn_readfirstlane(sc);
            const float eo = __expf(sc - m);
            float a0 = 0.f, a1 = 0.f, a2 = 0.f, a3 = 0.f;
#pragma unroll
            for (int i = 0; i < NT; i += 4) {
                a0 = fmaf(rl(eo, i+0), etr[i+0], a0);
                a1 = fmaf(rl(eo, i+1), etr[i+1], a1);
                a2 = fmaf(rl(eo, i+2), etr[i+2], a2);
                a3 = fmaf(rl(eo, i+3), etr[i+3], a3);
            }
            sc = m + __logf((a0 + a1) + (a2 + a3)) + em;
        }
        // combines: alpha_out[j] = LSE_i(alpha_in[i] + M_c[i][j]),
        // double-shifted: by lane-0 alpha (m_a) and by M row 0 (Mr_j).
        for (int cc = 0; cc < NCH-1; ++cc) {
            const float* Ml = &fc_lds[1024 + cc*NT*NT];
            const float m_a = __builtin_amdgcn_readfirstlane(sc);
            const float eo  = __expf(sc - m_a);
            const float Mr  = Ml[j];                 // i = 0 row
            float a0 = 0.f, a1 = 0.f, a2 = 0.f, a3 = 0.f;
#pragma unroll
            for (int i = 0; i < NT; i += 4) {
                a0 = fmaf(rl(eo, i+0), __expf(Ml[(i+0)*NT + j] - Mr), a0);
                a1 = fmaf(rl(eo, i+1), __expf(Ml[(i+1)*NT + j] - Mr), a1);
                a2 = fmaf(rl(eo, i+2), __expf(Ml[(i+2)*NT + j] - Mr), a2);
                a3 = fmaf(rl(eo, i+3), __expf(Ml[(i+3)*NT + j] - Mr), a3);
            }
            sc = m_a + Mr + __logf((a0 + a1) + (a2 + a3));
        }
        float v = (lane < NT) ? sc + end_t[j] : -1e30f;
        float m2 = v;
#pragma unroll
        for (int off = 32; off >= 1; off >>= 1) m2 = fmaxf(m2, __shfl_xor(m2, off));
        float e = (lane < NT) ? __expf(v - m2) : 0.f;
#pragma unroll
        for (int off = 32; off >= 1; off >>= 1) e += __shfl_xor(e, off);
        if (lane == 0) den[b] = m2 + __logf(e);
    } else {
        // ---- bulk-stage emissions into LDS: 12288 floats ----
#pragma unroll
        for (int i = 0; i < SS*NT/256; ++i) {
            const int idx = i*256 + lane*4;
            *(float4*)&fc_lds[idx] = *(const float4*)(fcb + idx);
        }
        __syncthreads();

        // ---- viterbi: half-split candidate argmax (bit-exact) ----
        const int jj   = lane & 31;
        const int jc   = (jj < NT) ? jj : 0;
        const int half = lane >> 5;
        const int cb   = half * 12;          // candidate base index

        float trC[12];
#pragma unroll
        for (int ii = 0; ii < 12; ++ii) trC[ii] = trans[(cb + ii)*NT + jc];

        float sc = start_t[jc] + fc_lds[jc];
        float em_next = fc_lds[NT + jc];
        for (int s = 1; s < SS; ++s) {
            float em = em_next;
            int snx = (s + 1 < SS) ? s + 1 : s;
            em_next = fc_lds[snx * NT + jc];
            float tv[12]; int ti[12];
#pragma unroll
            for (int ii = 0; ii < 12; ++ii) {
                tv[ii] = __shfl(sc, cb + ii) + trC[ii];
                ti[ii] = cb + ii;
            }
#pragma unroll
            for (int st = 1; st < 12; st <<= 1)
#pragma unroll
                for (int i = 0; i + st < 12; i += 2*st)
                    if (tv[i+st] > tv[i]) { tv[i] = tv[i+st]; ti[i] = ti[i+st]; }
            float ov = __shfl_xor(tv[0], 32);
            int   oi = __shfl_xor(ti[0], 32);
            float bv = tv[0]; int bi2 = ti[0];
            if (ov > bv || (ov == bv && oi < bi2)) { bv = ov; bi2 = oi; }
            sc = bv + em;
            if (lane < NT) hist[(s-1)*NT + lane] = (unsigned char)bi2;
        }
        float bv = (lane < NT) ? sc + end_t[jc] : -1e30f;
        int bi = (lane < NT) ? lane : NT;
#pragma unroll
        for (int off = 32; off >= 1; off >>= 1) {
            float ov = __shfl_xor(bv, off);
            int   oi = __shfl_xor(bi, off);
            if (ov > bv || (ov == bv && oi < bi)) { bv = ov; bi = oi; }
        }
        __syncthreads();   // drain LDS history writes

        // ---- backtrack, reach-2 composed ----
        unsigned char* C0 = hist;
        unsigned char* C1 = (unsigned char*)fc_lds;   // emissions dead now
        if (lane < 48) {
            const int t24 = (lane < 24) ? lane : lane - 24;
            const int h0c = (lane < 24) ? 1 : 3;
#pragma unroll 4
            for (int k = 0; k < 128; ++k) {
                int h = h0c + 4*k;
                if (h <= 509) {
                    int u = C0[(h+1)*NT + t24];
                    C1[h*NT + t24] = C0[h*NT + u];
                }
            }
        }
        __syncthreads();
        if (lane == 0) {
            int tg = bi;                 // tag @ 511
            anchor[SS-1] = (unsigned char)tg;
            for (int h = SS-3; h >= 1; h -= 2) {   // 509,507,...,1
                tg = C1[h*NT + tg];
                anchor[h] = (unsigned char)tg;
            }
        }
        __syncthreads();
        for (int s = lane; s < SS; s += 64) {
            int tag;
            if (s == SS-1)      tag = anchor[SS-1];
            else if (s & 1)     tag = anchor[s];
            else                tag = C0[s*NT + anchor[s+1]];
            crf_out[(size_t)b*SS + s] = (float)tag;
        }
    }
}

// =====================================================================
// Final scalar: -llh = -( sum_b(num[b]-den[b]) / 16384 )
// =====================================================================
__global__ __launch_bounds__(64) void llh_kernel(
    const float* __restrict__ num, const float* __restrict__ den,
    float* __restrict__ out)
{
    int t = threadIdx.x;
    float v = (t < BB) ? (num[t] - den[t]) : 0.f;
#pragma unroll
    for (int off = 32; off >= 1; off >>= 1) v += __shfl_xor(v, off);
    if (t == 0) out[(size_t)MR * 3] = -(v / (float)MR);
}

extern "C" void kernel_launch(void* const* d_in, const int* in_sizes, int n_in,
                              void* d_out, int out_size, void* d_ws, size_t ws_size,
                              hipStream_t stream) {
    const float* enc     = (const float*)d_in[0];
    const int*   labels  = (const int*)  d_in[1];
    // d_in[2] = mask (all ones by construction; unused)
    const float* Win     = (const float*)d_in[3];
    const float* bin     = (const float*)d_in[4];
    const float* Wout    = (const float*)d_in[5];
    const float* bout    = (const float*)d_in[6];
    const float* crf_w   = (const float*)d_in[7];
    const float* crf_b   = (const float*)d_in[8];
    const float* start_t = (const float*)d_in[9];
    const float* end_t   = (const float*)d_in[10];
    const float* trans   = (const float*)d_in[11];
    const float* ent_w   = (const float*)d_in[12];
    const float* ent_b   = (const float*)d_in[13];
    float* out = (float*)d_out;

    // Workspace layout — scores half (33.5 MB) aliases dec; scores are
    // dead before dec is written.  qkv is dead after step 3, so the
    // forward transfer matrices (1.1 MB) reuse it.
    float* ws   = (float*)d_ws;
    float* qkv  = ws;                                 // 16384*1536
    float* attn = qkv  + (size_t)MR * E3;             // 16384*512
    float* big  = attn + (size_t)MR * EE;             // 8,388,608 floats
    float* sch  = big;                                // scores half: 32*512*512
    float* dec  = big;                                // dec aliases scores
    float* fc   = big  + (size_t)MR * EE;             // 16384*24
    float* num  = fc   + (size_t)MR * NT;             // 32
    float* den  = num  + BB;                          // 32
    float* Mws  = qkv;                                // 32*15*24*24 (reuse)

    dim3 blk(256);
    // 1. qkv = enc @ Win^T + bin
    mfma_gemm<0><<<dim3(E3/128, MR/128, 1), blk, 0, stream>>>(
        enc, EE, 0, 0, 0,  Win, EE, 0, 0, 0,  bin,
        qkv, E3, 0, 0, 0,  EE, 0);
    // 2. attention in two z-passes of 32 (b,h) pairs each
    for (int p = 0; p < 2; ++p) {
        int zoff = p * 32;
        // scores[z][m][n] = Q[m].K[n]
        mfma_gemm<0><<<dim3(SS/128, SS/128, 32), blk, 0, stream>>>(
            qkv,      E3, (long)SS*E3, HDD, zoff,
            qkv + EE, E3, (long)SS*E3, HDD, zoff,
            nullptr,
            sch, SS, 2L*SS*SS, (long)SS*SS, 0,
            HDD, 0);
        softmax_rows<<<(32*SS)/4, blk, 0, stream>>>(sch);
        // attn[b,m,h*256+n] = sum_k P[z][m][k] V[b,k,h][n]
        mfma_gemm<1><<<dim3(HDD/128, SS/128, 32), blk, 0, stream>>>(
            sch, SS, 2L*SS*SS, (long)SS*SS, 0,
            qkv + 2*EE, E3, (long)SS*E3, HDD, zoff,
            nullptr,
            attn, EE, (long)SS*EE, HDD, zoff,
            SS, 0);
    }
    // 3. dec = relu(attn @ Wout^T + bout)   (overwrites scores region)
    mfma_gemm<0><<<dim3(EE/128, MR/128, 1), blk, 0, stream>>>(
        attn, EE, 0, 0, 0,  Wout, EE, 0, 0, 0,  bout,
        dec, EE, 0, 0, 0,  EE, 1);
    // 4. fc emissions
    fc_crf_kernel<<<MR/8, dim3(192), 0, stream>>>(dec, crf_w, crf_b, fc);
    // 4b. forward-scan phase A: per-chunk transfer matrices (parallel)
    fwd_chunks_kernel<<<dim3(BB*(NCH-1)*NT/4), blk, 0, stream>>>(fc, trans, Mws);
    // 5. CRF (forward-combine+viterbi+numerator) + seg head
    crf_seg_kernel<<<96 + MR/8, dim3(64), 0, stream>>>(
        fc, labels, start_t, end_t, trans, dec, ent_w, ent_b,
        num, den, out, out + MR, Mws);
    // 6. -llh scalar -> d_out[49152]
    llh_kernel<<<1, 64, 0, stream>>>(num, den, out);
}

// Round 4
// 591.489 us; speedup vs baseline: 1.0392x; 1.0392x over previous
//
#include <hip/hip_runtime.h>

#define BB 32
#define SS 512
#define EE 512
#define NHH 2
#define HDD 256
#define E3 1536
#define NT 24
#define MR (BB*SS)   // 16384

typedef _Float16 half8  __attribute__((ext_vector_type(8)));
typedef _Float16 half4v __attribute__((ext_vector_type(4)));
typedef float    f32x4  __attribute__((ext_vector_type(4)));

// scalar (SGPR) lane broadcast — index MUST be wave-uniform.
__device__ __forceinline__ float rl(float v, int l) {
    return __int_as_float(__builtin_amdgcn_readlane(__float_as_int(v), l));
}

// gfx950 v_permlane32_swap_b32 semantics: vdst.hi <-> vsrc.lo.
// With b seeded as a copy of a==X (INSIDE the asm, so the compiler
// cannot alias a and b to one VGPR — that aliasing was round-13's bug:
// self-swap produced garbage -> hist bytes of 255 -> absmax 253):
//   after: a = {X.lo, X.lo},  b = {X.hi, X.hi}
// Lane l<32 reads partner (l+32) from b; lane l>=32 reads (l-32) from a.
__device__ __forceinline__ float swap32_f(float x, int half) {
    int a = __float_as_int(x), b;
    asm volatile("v_mov_b32 %1, %0\n\t"
                 "v_permlane32_swap_b32 %0, %1"
                 : "+v"(a), "=&v"(b));
    return __int_as_float(half ? a : b);
}
__device__ __forceinline__ int swap32_i(int x, int half) {
    int a = x, b;
    asm volatile("v_mov_b32 %1, %0\n\t"
                 "v_permlane32_swap_b32 %0, %1"
                 : "+v"(a), "=&v"(b));
    return half ? a : b;
}

// =====================================================================
// fp32-accurate GEMM via fp16 3-product MFMA split (Ootomo).
// 128x128 block tile, 256 thr = 2x2 waves, 4x4 tiles of 16x16x32 f16.
// BN=0: B is row-major N x K (B^T form). BN=1: B is row-major K x N (V).
// =====================================================================
template<int BN>
__global__ __launch_bounds__(256) void mfma_gemm(
    const float* __restrict__ A, int lda, long sAhi, long sAlo, int zA,
    const float* __restrict__ B, int ldb, long sBhi, long sBlo, int zB,
    const float* __restrict__ bias,
    float* __restrict__ C, int ldc, long sChi, long sClo, int zC,
    int K, int relu)
{
    __shared__ __align__(16) _Float16 sAh[8*640];
    __shared__ __align__(16) _Float16 sAl[8*640];
    __shared__ __align__(16) _Float16 sBh[8*640];
    __shared__ __align__(16) _Float16 sBl[8*640];

    const int t = threadIdx.x;
    const int z = blockIdx.z;
    const int za = zA + z, zb = zB + z, zc = zC + z;
    const float* Ab = A + (size_t)(za>>1)*sAhi + (size_t)(za&1)*sAlo
                        + (size_t)blockIdx.y*128*lda;
    const float* Bb = B + (size_t)(zb>>1)*sBhi + (size_t)(zb&1)*sBlo
                        + (BN ? (size_t)blockIdx.x*128
                              : (size_t)blockIdx.x*128*ldb);

    const int wv = t >> 6, lane = t & 63;
    const int wm = wv >> 1, wn = wv & 1;
    const int lm = lane & 15, lq = lane >> 4;

    f32x4 acc[4][4];
#pragma unroll
    for (int i = 0; i < 4; ++i)
#pragma unroll
        for (int j = 0; j < 4; ++j) acc[i][j] = (f32x4){0.f,0.f,0.f,0.f};

    const int r8  = t >> 3;         // 0..31 (staging row base)
    const int kc  = (t & 7) * 4;    // 0..28 (staging k chunk)
    const int bnk = (t >> 7) * 16;  // BN staging: k half
    const int bnn = t & 127;        // BN staging: n

    for (int k0 = 0; k0 < K; k0 += 32) {
        float4 ga[4], gb[4]; float gv[16];
#pragma unroll
        for (int i = 0; i < 4; ++i)
            ga[i] = *(const float4*)(Ab + (size_t)(r8 + 32*i)*lda + k0 + kc);
        if (BN) {
#pragma unroll
            for (int i = 0; i < 16; ++i)
                gv[i] = Bb[(size_t)(k0 + bnk + i)*ldb + bnn];
        } else {
#pragma unroll
            for (int i = 0; i < 4; ++i)
                gb[i] = *(const float4*)(Bb + (size_t)(r8 + 32*i)*ldb + k0 + kc);
        }
        __syncthreads();   // previous iteration's fragment reads complete
#pragma unroll
        for (int i = 0; i < 4; ++i) {
            const int row  = r8 + 32*i;
            const int base = (row >> 4)*640 + (row & 15)*40 + kc;
            float4 a = ga[i];
            _Float16 h0 = (_Float16)a.x, h1 = (_Float16)a.y,
                     h2 = (_Float16)a.z, h3 = (_Float16)a.w;
            _Float16 l0 = (_Float16)(a.x - (float)h0),
                     l1 = (_Float16)(a.y - (float)h1),
                     l2 = (_Float16)(a.z - (float)h2),
                     l3 = (_Float16)(a.w - (float)h3);
            *(half4v*)&sAh[base] = (half4v){h0,h1,h2,h3};
            *(half4v*)&sAl[base] = (half4v){l0,l1,l2,l3};
        }
        if (BN) {
#pragma unroll
            for (int i = 0; i < 16; ++i) {
                const int k = bnk + i;
                float v = gv[i];
                _Float16 h = (_Float16)v;
                _Float16 l = (_Float16)(v - (float)h);
                const int base = (bnn >> 4)*640 + (bnn & 15)*40 + k;
                sBh[base] = h;
                sBl[base] = l;
            }
        } else {
#pragma unroll
            for (int i = 0; i < 4; ++i) {
                const int row  = r8 + 32*i;
                const int base = (row >> 4)*640 + (row & 15)*40 + kc;
                float4 b = gb[i];
                _Float16 h0 = (_Float16)b.x, h1 = (_Float16)b.y,
                         h2 = (_Float16)b.z, h3 = (_Float16)b.w;
                _Float16 l0 = (_Float16)(b.x - (float)h0),
                         l1 = (_Float16)(b.y - (float)h1),
                         l2 = (_Float16)(b.z - (float)h2),
                         l3 = (_Float16)(b.w - (float)h3);
                *(half4v*)&sBh[base] = (half4v){h0,h1,h2,h3};
                *(half4v*)&sBl[base] = (half4v){l0,l1,l2,l3};
            }
        }
        __syncthreads();

        half8 bhf[4], blf[4];
#pragma unroll
        for (int j = 0; j < 4; ++j) {
            const int tb = (wn*4 + j)*640 + lm*40 + lq*8;
            bhf[j] = *(const half8*)&sBh[tb];
            blf[j] = *(const half8*)&sBl[tb];
        }
#pragma unroll
        for (int i = 0; i < 4; ++i) {
            const int ta = (wm*4 + i)*640 + lm*40 + lq*8;
            half8 ah = *(const half8*)&sAh[ta];
            half8 al = *(const half8*)&sAl[ta];
#pragma unroll
            for (int j = 0; j < 4; ++j) {
                acc[i][j] = __builtin_amdgcn_mfma_f32_16x16x32_f16(ah, bhf[j], acc[i][j], 0, 0, 0);
                acc[i][j] = __builtin_amdgcn_mfma_f32_16x16x32_f16(al, bhf[j], acc[i][j], 0, 0, 0);
                acc[i][j] = __builtin_amdgcn_mfma_f32_16x16x32_f16(ah, blf[j], acc[i][j], 0, 0, 0);
            }
        }
    }

    // epilogue: C/D layout col = lane&15, row = quad*4 + reg
    float* Cb = C + (size_t)(zc>>1)*sChi + (size_t)(zc&1)*sClo;
#pragma unroll
    for (int j = 0; j < 4; ++j) {
        const int col = blockIdx.x*128 + (wn*4 + j)*16 + lm;
        const float bj = bias ? bias[col] : 0.f;
#pragma unroll
        for (int i = 0; i < 4; ++i) {
            const int row0 = blockIdx.y*128 + (wm*4 + i)*16 + lq*4;
#pragma unroll
            for (int r = 0; r < 4; ++r) {
                float v = acc[i][j][r] + bj;
                if (relu) v = fmaxf(v, 0.f);
                Cb[(size_t)(row0 + r)*ldc + col] = v;
            }
        }
    }
}

// =====================================================================
// Row softmax over scores (in place, fully normalized).
// =====================================================================
__global__ __launch_bounds__(256) void softmax_rows(float* __restrict__ scores)
{
    const int w    = threadIdx.x >> 6;
    const int lane = threadIdx.x & 63;
    const size_t row = (size_t)blockIdx.x * 4 + w;
    float* p = scores + row * SS + lane * 8;
    float4 v0 = *(float4*)(p);
    float4 v1 = *(float4*)(p + 4);
    const float scale = 0.0625f;
    float m = fmaxf(fmaxf(fmaxf(v0.x, v0.y), fmaxf(v0.z, v0.w)),
                    fmaxf(fmaxf(v1.x, v1.y), fmaxf(v1.z, v1.w)));
#pragma unroll
    for (int off = 32; off >= 1; off >>= 1) m = fmaxf(m, __shfl_xor(m, off));
    v0.x = __expf((v0.x - m) * scale); v0.y = __expf((v0.y - m) * scale);
    v0.z = __expf((v0.z - m) * scale); v0.w = __expf((v0.w - m) * scale);
    v1.x = __expf((v1.x - m) * scale); v1.y = __expf((v1.y - m) * scale);
    v1.z = __expf((v1.z - m) * scale); v1.w = __expf((v1.w - m) * scale);
    float sum = v0.x + v0.y + v0.z + v0.w + v1.x + v1.y + v1.z + v1.w;
#pragma unroll
    for (int off = 32; off >= 1; off >>= 1) sum += __shfl_xor(sum, off);
    float inv = 1.f / sum;
    v0.x *= inv; v0.y *= inv; v0.z *= inv; v0.w *= inv;
    v1.x *= inv; v1.y *= inv; v1.z *= inv; v1.w *= inv;
    *(float4*)(p)     = v0;
    *(float4*)(p + 4) = v1;
}

// =====================================================================
// CRF emissions: fc[row][j] = dot(dec[row], crf_w[j]) + crf_b[j]
// =====================================================================
__global__ __launch_bounds__(192) void fc_crf_kernel(
    const float* __restrict__ dec, const float* __restrict__ W,
    const float* __restrict__ bias, float* __restrict__ out)
{
    __shared__ __align__(16) float Ws[NT][516];
    for (int i = threadIdx.x; i < NT*128; i += 192) {
        int j = i >> 7, c = (i & 127) * 4;
        *(float4*)&Ws[j][c] = *(const float4*)(W + (size_t)j*EE + c);
    }
    __syncthreads();
    const int t = threadIdx.x;
    const int rloc = t / NT;
    const int j = t - rloc * NT;
    const int row = blockIdx.x * 8 + rloc;
    const float4* a = (const float4*)(dec + (size_t)row * EE);
    float acc = 0.f;
#pragma unroll 4
    for (int i = 0; i < 128; ++i) {
        float4 x = a[i];
        float4 y = *(const float4*)&Ws[j][i*4];
        acc += x.x*y.x + x.y*y.y + x.z*y.z + x.w*y.w;
    }
    out[(size_t)row * NT + j] = acc + bias[j];
}

// =====================================================================
// CRF + seg, 64-thread blocks.
// blocks 0..95: CRF tasks (forward / viterbi / numerator per batch).
// blocks >= 96: seg head, 8 rows per block.
// Round-14 = round-13 with the permlane32_swap aliasing bug fixed
// (forced-distinct registers; see swap32_* comment).  Viterbi step:
// half-split candidates, v_readlane broadcasts + permlane32_swap
// combine — zero LDS ops in the cross-lane path.  Bit-exact
// (first-tie-lowest-global-index, same as r10/r11).
// =====================================================================
__global__ __launch_bounds__(64, 1) void crf_seg_kernel(
    const float* __restrict__ fc, const int* __restrict__ labels,
    const float* __restrict__ start_t, const float* __restrict__ end_t,
    const float* __restrict__ trans, const float* __restrict__ dec,
    const float* __restrict__ ent_w, const float* __restrict__ ent_b,
    float* __restrict__ num, float* __restrict__ den,
    float* __restrict__ crf_out, float* __restrict__ segout)
{
    __shared__ __align__(16) float fc_lds[SS*NT];     // 48 KB (viterbi: reused as C1 scratch after recursion)
    __shared__ unsigned char hist[(SS-1)*NT];         // 12 KB  (C0)
    __shared__ unsigned char anchor[SS];              // backtrack anchors

    const int blk  = blockIdx.x;
    const int lane = threadIdx.x;

    if (blk >= 96) {
        // ---------------- segmentation head: 8 rows per block -----------
        const int row0 = (blk - 96) * 8;
        const float4* w0 = (const float4*)(ent_w);
        const float4* w1 = (const float4*)(ent_w + EE);
        const int i0 = lane * 2, i1 = lane * 2 + 1;
        const float4 u0 = w0[i0], u1 = w0[i1];
        const float4 q0 = w1[i0], q1 = w1[i1];
        const float eb0 = ent_b[0], eb1 = ent_b[1];
#pragma unroll 2
        for (int r = 0; r < 8; ++r) {
            const int row = row0 + r;
            const float4* a = (const float4*)(dec + (size_t)row * EE);
            float acc0 = 0.f, acc1 = 0.f;
            {
                float4 x = a[i0];
                acc0 += x.x*u0.x + x.y*u0.y + x.z*u0.z + x.w*u0.w;
                acc1 += x.x*q0.x + x.y*q0.y + x.z*q0.z + x.w*q0.w;
            }
            {
                float4 x = a[i1];
                acc0 += x.x*u1.x + x.y*u1.y + x.z*u1.z + x.w*u1.w;
                acc1 += x.x*q1.x + x.y*q1.y + x.z*q1.z + x.w*q1.w;
            }
#pragma unroll
            for (int off = 32; off >= 1; off >>= 1) {
                acc0 += __shfl_xor(acc0, off);
                acc1 += __shfl_xor(acc1, off);
            }
            if (lane == 0) {
                float l0 = acc0 + eb0;
                float l1 = acc1 + eb1;
                float m  = fmaxf(l0, l1);
                float lse = m + __logf(__expf(l0 - m) + __expf(l1 - m));
                segout[(size_t)row*2 + 0] = l0 - lse;
                segout[(size_t)row*2 + 1] = l1 - lse;
            }
        }
        return;
    }

    const int role = blk >> 5;          // 0=forward, 1=viterbi, 2=numerator
    const int b    = blk & 31;
    const float* fcb = fc + (size_t)b * SS * NT;

    if (role == 2) {
        // ---- numerator (one pass, already parallel; no LDS needed) ----
        float acc = 0.f;
        for (int s = 1 + lane; s < SS; s += 64) {
            int prev = labels[b*SS + s - 1];
            int cur  = labels[b*SS + s];
            acc += trans[prev*NT + cur] + fcb[(size_t)s*NT + cur];
        }
        if (lane == 0) {
            int l0 = labels[b*SS];
            acc += start_t[l0] + fcb[l0] + end_t[labels[b*SS + SS - 1]];
        }
#pragma unroll
        for (int off = 32; off >= 1; off >>= 1) acc += __shfl_xor(acc, off);
        if (lane == 0) num[b] = acc;
        return;
    }

    // ---- bulk-stage emissions into LDS: 12288 floats, 48 float4/lane ----
#pragma unroll
    for (int i = 0; i < SS*NT/256; ++i) {
        const int idx = i*256 + lane*4;
        *(float4*)&fc_lds[idx] = *(const float4*)(fcb + idx);
    }
    __syncthreads();

    // lane j<24 owns destination tag j
    const int j = (lane < NT) ? lane : 0;

    if (role == 0) {
        // ---- forward (log-normalizer), serial — bit-exact den ----
        float sc = start_t[j] + fc_lds[j];
        float etr[NT];
#pragma unroll
        for (int i = 0; i < NT; ++i) etr[i] = __expf(trans[i*NT + j]);
        float em_next = fc_lds[NT + j];
        for (int s = 1; s < SS; ++s) {
            float em = em_next;
            int snx = (s + 1 < SS) ? s + 1 : s;
            em_next = fc_lds[snx * NT + j];          // LDS prefetch
            const float m  = __builtin_amdgcn_readfirstlane(sc);
            const float eo = __expf(sc - m);          // 1 exp per lane
            float a0 = 0.f, a1 = 0.f, a2 = 0.f, a3 = 0.f;
#pragma unroll
            for (int i = 0; i < NT; i += 4) {
                a0 = fmaf(rl(eo, i+0), etr[i+0], a0);
                a1 = fmaf(rl(eo, i+1), etr[i+1], a1);
                a2 = fmaf(rl(eo, i+2), etr[i+2], a2);
                a3 = fmaf(rl(eo, i+3), etr[i+3], a3);
            }
            sc = m + __logf((a0 + a1) + (a2 + a3)) + em;
        }
        float v = (lane < NT) ? sc + end_t[j] : -1e30f;
        float m2 = v;
#pragma unroll
        for (int off = 32; off >= 1; off >>= 1) m2 = fmaxf(m2, __shfl_xor(m2, off));
        float e = (lane < NT) ? __expf(v - m2) : 0.f;
#pragma unroll
        for (int off = 32; off >= 1; off >>= 1) e += __shfl_xor(e, off);
        if (lane == 0) den[b] = m2 + __logf(e);
    } else {
        // ---- viterbi: half-split argmax, readlane + permlane32_swap ----
        // dest tag jj = lane&31 (valid <24); half h = lane>>5 owns
        // candidates h*12 .. h*12+11.  Values & first-tie-lowest-index
        // semantics bit-identical to r10's 24-wide serial tree.
        const int jj   = lane & 31;
        const int jc   = (jj < NT) ? jj : 0;
        const int half = lane >> 5;
        const int cb   = half * 12;          // candidate base index

        float trC[12];
#pragma unroll
        for (int ii = 0; ii < 12; ++ii) trC[ii] = trans[(cb + ii)*NT + jc];

        // sc is valid in lanes 0..23 (and replicated into 32..55 by the
        // combine); readlane broadcasts always source lanes 0..23.
        float sc = start_t[jc] + fc_lds[jc];
        float em_next = fc_lds[NT + jc];
        for (int s = 1; s < SS; ++s) {
            float em = em_next;
            int snx = (s + 1 < SS) ? s + 1 : s;
            em_next = fc_lds[snx * NT + jc];
            float tv[12]; int ti[12];
#pragma unroll
            for (int ii = 0; ii < 12; ++ii) {
                // wave-uniform scalar broadcasts (VALU readlane, no LDS)
                float slo = rl(sc, ii);
                float shi = rl(sc, 12 + ii);
                float sv  = half ? shi : slo;     // 1 cndmask
                tv[ii] = sv + trC[ii];
                ti[ii] = cb + ii;
            }
            // first-tie argmax tree over the 12 owned candidates
#pragma unroll
            for (int st = 1; st < 12; st <<= 1)
#pragma unroll
                for (int i = 0; i + st < 12; i += 2*st)
                    if (tv[i+st] > tv[i]) { tv[i] = tv[i+st]; ti[i] = ti[i+st]; }
            // cross-half combine via permlane32_swap (VALU, no LDS)
            float ov = swap32_f(tv[0], half);
            int   oi = swap32_i(ti[0], half);
            float bv = tv[0]; int bi2 = ti[0];
            if (ov > bv || (ov == bv && oi < bi2)) { bv = ov; bi2 = oi; }
            sc = bv + em;
            if (lane < NT) hist[(s-1)*NT + lane] = (unsigned char)bi2;
        }
        // final argmax over lanes (first-tie, lowest lane wins)
        float bv = (lane < NT) ? sc + end_t[jc] : -1e30f;
        int bi = (lane < NT) ? lane : NT;
#pragma unroll
        for (int off = 32; off >= 1; off >>= 1) {
            float ov = __shfl_xor(bv, off);
            int   oi = __shfl_xor(bi, off);
            if (ov > bv || (ov == bv && oi < bi)) { bv = ov; bi = oi; }
        }
        __syncthreads();   // drain LDS history writes

        // ---- backtrack, reach-2 composed ----
        // C0[h][t] = tag@h given tag@(h+1)=t,  h in 0..510  (== hist)
        // C1[h][t] = C0[h][C0[h+1][t]]         (odd h only; reach 2)
        unsigned char* C0 = hist;
        unsigned char* C1 = (unsigned char*)fc_lds;   // emissions dead now
        if (lane < 48) {
            const int t24 = (lane < 24) ? lane : lane - 24;
            const int h0c = (lane < 24) ? 1 : 3;
#pragma unroll 4
            for (int k = 0; k < 128; ++k) {
                int h = h0c + 4*k;
                if (h <= 509) {
                    int u = C0[(h+1)*NT + t24];
                    C1[h*NT + t24] = C0[h*NT + u];
                }
            }
        }
        __syncthreads();
        if (lane == 0) {
            int tg = bi;                 // tag @ 511
            anchor[SS-1] = (unsigned char)tg;
            for (int h = SS-3; h >= 1; h -= 2) {   // 509,507,...,1
                tg = C1[h*NT + tg];
                anchor[h] = (unsigned char)tg;
            }
        }
        __syncthreads();
        for (int s = lane; s < SS; s += 64) {
            int tag;
            if (s == SS-1)      tag = anchor[SS-1];
            else if (s & 1)     tag = anchor[s];
            else                tag = C0[s*NT + anchor[s+1]];
            crf_out[(size_t)b*SS + s] = (float)tag;
        }
    }
}

// =====================================================================
// Final scalar: -llh = -( sum_b(num[b]-den[b]) / 16384 )
// =====================================================================
__global__ __launch_bounds__(64) void llh_kernel(
    const float* __restrict__ num, const float* __restrict__ den,
    float* __restrict__ out)
{
    int t = threadIdx.x;
    float v = (t < BB) ? (num[t] - den[t]) : 0.f;
#pragma unroll
    for (int off = 32; off >= 1; off >>= 1) v += __shfl_xor(v, off);
    if (t == 0) out[(size_t)MR * 3] = -(v / (float)MR);
}

extern "C" void kernel_launch(void* const* d_in, const int* in_sizes, int n_in,
                              void* d_out, int out_size, void* d_ws, size_t ws_size,
                              hipStream_t stream) {
    const float* enc     = (const float*)d_in[0];
    const int*   labels  = (const int*)  d_in[1];
    // d_in[2] = mask (all ones by construction; unused)
    const float* Win     = (const float*)d_in[3];
    const float* bin     = (const float*)d_in[4];
    const float* Wout    = (const float*)d_in[5];
    const float* bout    = (const float*)d_in[6];
    const float* crf_w   = (const float*)d_in[7];
    const float* crf_b   = (const float*)d_in[8];
    const float* start_t = (const float*)d_in[9];
    const float* end_t   = (const float*)d_in[10];
    const float* trans   = (const float*)d_in[11];
    const float* ent_w   = (const float*)d_in[12];
    const float* ent_b   = (const float*)d_in[13];
    float* out = (float*)d_out;

    // Workspace layout — scores half (33.5 MB) aliases dec; scores are
    // dead before dec is written.
    float* ws   = (float*)d_ws;
    float* qkv  = ws;                                 // 16384*1536
    float* attn = qkv  + (size_t)MR * E3;             // 16384*512
    float* big  = attn + (size_t)MR * EE;             // 8,388,608 floats
    float* sch  = big;                                // scores half: 32*512*512
    float* dec  = big;                                // dec aliases scores
    float* fc   = big  + (size_t)MR * EE;             // 16384*24
    float* num  = fc   + (size_t)MR * NT;             // 32
    float* den  = num  + BB;                          // 32

    dim3 blk(256);
    // 1. qkv = enc @ Win^T + bin
    mfma_gemm<0><<<dim3(E3/128, MR/128, 1), blk, 0, stream>>>(
        enc, EE, 0, 0, 0,  Win, EE, 0, 0, 0,  bin,
        qkv, E3, 0, 0, 0,  EE, 0);
    // 2. attention in two z-passes of 32 (b,h) pairs each
    for (int p = 0; p < 2; ++p) {
        int zoff = p * 32;
        // scores[z][m][n] = Q[m].K[n]
        mfma_gemm<0><<<dim3(SS/128, SS/128, 32), blk, 0, stream>>>(
            qkv,      E3, (long)SS*E3, HDD, zoff,
            qkv + EE, E3, (long)SS*E3, HDD, zoff,
            nullptr,
            sch, SS, 2L*SS*SS, (long)SS*SS, 0,
            HDD, 0);
        softmax_rows<<<(32*SS)/4, blk, 0, stream>>>(sch);
        // attn[b,m,h*256+n] = sum_k P[z][m][k] V[b,k,h][n]
        mfma_gemm<1><<<dim3(HDD/128, SS/128, 32), blk, 0, stream>>>(
            sch, SS, 2L*SS*SS, (long)SS*SS, 0,
            qkv + 2*EE, E3, (long)SS*E3, HDD, zoff,
            nullptr,
            attn, EE, (long)SS*EE, HDD, zoff,
            SS, 0);
    }
    // 3. dec = relu(attn @ Wout^T + bout)   (overwrites scores region)
    mfma_gemm<0><<<dim3(EE/128, MR/128, 1), blk, 0, stream>>>(
        attn, EE, 0, 0, 0,  Wout, EE, 0, 0, 0,  bout,
        dec, EE, 0, 0, 0,  EE, 1);
    // 4. fc emissions
    fc_crf_kernel<<<MR/8, dim3(192), 0, stream>>>(dec, crf_w, crf_b, fc);
    // 5. CRF (forward+viterbi+numerator) + seg head (8 rows/block)
    crf_seg_kernel<<<96 + MR/8, dim3(64), 0, stream>>>(
        fc, labels, start_t, end_t, trans, dec, ent_w, ent_b,
        num, den, out, out + MR);
    // 6. -llh scalar -> d_out[49152]
    llh_kernel<<<1, 64, 0, stream>>>(num, den, out);
}

// Round 5
// 573.815 us; speedup vs baseline: 1.0712x; 1.0308x over previous
//
#include <hip/hip_runtime.h>

#define BB 32
#define SS 512
#define EE 512
#define NHH 2
#define HDD 256
#define E3 1536
#define NT 24
#define MR (BB*SS)   // 16384

typedef _Float16 half8  __attribute__((ext_vector_type(8)));
typedef _Float16 half4v __attribute__((ext_vector_type(4)));
typedef float    f32x4  __attribute__((ext_vector_type(4)));

// scalar (SGPR) lane broadcast — index MUST be wave-uniform.
__device__ __forceinline__ float rl(float v, int l) {
    return __int_as_float(__builtin_amdgcn_readlane(__float_as_int(v), l));
}

// =====================================================================
// fp32-accurate GEMM via fp16 3-product MFMA split (Ootomo).
// 128x128 block tile, 256 thr = 2x2 waves, 4x4 tiles of 16x16x32 f16.
// BN=0: B is row-major N x K (B^T form). BN=1: B is row-major K x N (V).
// Round-15: BN=1 staging vectorized — 4x float4 loads along n replaces
// 16 scalar dword loads (the only scalar global loads in the pipeline).
// Same LDS layout, bit-identical values.
// =====================================================================
template<int BN>
__global__ __launch_bounds__(256) void mfma_gemm(
    const float* __restrict__ A, int lda, long sAhi, long sAlo, int zA,
    const float* __restrict__ B, int ldb, long sBhi, long sBlo, int zB,
    const float* __restrict__ bias,
    float* __restrict__ C, int ldc, long sChi, long sClo, int zC,
    int K, int relu)
{
    __shared__ __align__(16) _Float16 sAh[8*640];
    __shared__ __align__(16) _Float16 sAl[8*640];
    __shared__ __align__(16) _Float16 sBh[8*640];
    __shared__ __align__(16) _Float16 sBl[8*640];

    const int t = threadIdx.x;
    const int z = blockIdx.z;
    const int za = zA + z, zb = zB + z, zc = zC + z;
    const float* Ab = A + (size_t)(za>>1)*sAhi + (size_t)(za&1)*sAlo
                        + (size_t)blockIdx.y*128*lda;
    const float* Bb = B + (size_t)(zb>>1)*sBhi + (size_t)(zb&1)*sBlo
                        + (BN ? (size_t)blockIdx.x*128
                              : (size_t)blockIdx.x*128*ldb);

    const int wv = t >> 6, lane = t & 63;
    const int wm = wv >> 1, wn = wv & 1;
    const int lm = lane & 15, lq = lane >> 4;

    f32x4 acc[4][4];
#pragma unroll
    for (int i = 0; i < 4; ++i)
#pragma unroll
        for (int j = 0; j < 4; ++j) acc[i][j] = (f32x4){0.f,0.f,0.f,0.f};

    const int r8  = t >> 3;         // 0..31 (staging row base)
    const int kc  = (t & 7) * 4;    // 0..28 (staging k chunk)
    const int bnn4 = (t & 31) * 4;  // BN staging: n base (0..124)
    const int bnk4 = (t >> 5) * 4;  // BN staging: k base (0..28)

    for (int k0 = 0; k0 < K; k0 += 32) {
        float4 ga[4], gb[4]; float4 gv4[4];
#pragma unroll
        for (int i = 0; i < 4; ++i)
            ga[i] = *(const float4*)(Ab + (size_t)(r8 + 32*i)*lda + k0 + kc);
        if (BN) {
#pragma unroll
            for (int kk = 0; kk < 4; ++kk)
                gv4[kk] = *(const float4*)(Bb + (size_t)(k0 + bnk4 + kk)*ldb + bnn4);
        } else {
#pragma unroll
            for (int i = 0; i < 4; ++i)
                gb[i] = *(const float4*)(Bb + (size_t)(r8 + 32*i)*ldb + k0 + kc);
        }
        __syncthreads();   // previous iteration's fragment reads complete
#pragma unroll
        for (int i = 0; i < 4; ++i) {
            const int row  = r8 + 32*i;
            const int base = (row >> 4)*640 + (row & 15)*40 + kc;
            float4 a = ga[i];
            _Float16 h0 = (_Float16)a.x, h1 = (_Float16)a.y,
                     h2 = (_Float16)a.z, h3 = (_Float16)a.w;
            _Float16 l0 = (_Float16)(a.x - (float)h0),
                     l1 = (_Float16)(a.y - (float)h1),
                     l2 = (_Float16)(a.z - (float)h2),
                     l3 = (_Float16)(a.w - (float)h3);
            *(half4v*)&sAh[base] = (half4v){h0,h1,h2,h3};
            *(half4v*)&sAl[base] = (half4v){l0,l1,l2,l3};
        }
        if (BN) {
#pragma unroll
            for (int kk = 0; kk < 4; ++kk) {
                const float vv[4] = {gv4[kk].x, gv4[kk].y, gv4[kk].z, gv4[kk].w};
#pragma unroll
                for (int nn = 0; nn < 4; ++nn) {
                    const int n = bnn4 + nn;
                    float v = vv[nn];
                    _Float16 h = (_Float16)v;
                    _Float16 l = (_Float16)(v - (float)h);
                    const int base = (n >> 4)*640 + (n & 15)*40 + bnk4 + kk;
                    sBh[base] = h;
                    sBl[base] = l;
                }
            }
        } else {
#pragma unroll
            for (int i = 0; i < 4; ++i) {
                const int row  = r8 + 32*i;
                const int base = (row >> 4)*640 + (row & 15)*40 + kc;
                float4 b = gb[i];
                _Float16 h0 = (_Float16)b.x, h1 = (_Float16)b.y,
                         h2 = (_Float16)b.z, h3 = (_Float16)b.w;
                _Float16 l0 = (_Float16)(b.x - (float)h0),
                         l1 = (_Float16)(b.y - (float)h1),
                         l2 = (_Float16)(b.z - (float)h2),
                         l3 = (_Float16)(b.w - (float)h3);
                *(half4v*)&sBh[base] = (half4v){h0,h1,h2,h3};
                *(half4v*)&sBl[base] = (half4v){l0,l1,l2,l3};
            }
        }
        __syncthreads();

        half8 bhf[4], blf[4];
#pragma unroll
        for (int j = 0; j < 4; ++j) {
            const int tb = (wn*4 + j)*640 + lm*40 + lq*8;
            bhf[j] = *(const half8*)&sBh[tb];
            blf[j] = *(const half8*)&sBl[tb];
        }
#pragma unroll
        for (int i = 0; i < 4; ++i) {
            const int ta = (wm*4 + i)*640 + lm*40 + lq*8;
            half8 ah = *(const half8*)&sAh[ta];
            half8 al = *(const half8*)&sAl[ta];
#pragma unroll
            for (int j = 0; j < 4; ++j) {
                acc[i][j] = __builtin_amdgcn_mfma_f32_16x16x32_f16(ah, bhf[j], acc[i][j], 0, 0, 0);
                acc[i][j] = __builtin_amdgcn_mfma_f32_16x16x32_f16(al, bhf[j], acc[i][j], 0, 0, 0);
                acc[i][j] = __builtin_amdgcn_mfma_f32_16x16x32_f16(ah, blf[j], acc[i][j], 0, 0, 0);
            }
        }
    }

    // epilogue: C/D layout col = lane&15, row = quad*4 + reg
    float* Cb = C + (size_t)(zc>>1)*sChi + (size_t)(zc&1)*sClo;
#pragma unroll
    for (int j = 0; j < 4; ++j) {
        const int col = blockIdx.x*128 + (wn*4 + j)*16 + lm;
        const float bj = bias ? bias[col] : 0.f;
#pragma unroll
        for (int i = 0; i < 4; ++i) {
            const int row0 = blockIdx.y*128 + (wm*4 + i)*16 + lq*4;
#pragma unroll
            for (int r = 0; r < 4; ++r) {
                float v = acc[i][j][r] + bj;
                if (relu) v = fmaxf(v, 0.f);
                Cb[(size_t)(row0 + r)*ldc + col] = v;
            }
        }
    }
}

// =====================================================================
// Row softmax over scores (in place, fully normalized).
// =====================================================================
__global__ __launch_bounds__(256) void softmax_rows(float* __restrict__ scores)
{
    const int w    = threadIdx.x >> 6;
    const int lane = threadIdx.x & 63;
    const size_t row = (size_t)blockIdx.x * 4 + w;
    float* p = scores + row * SS + lane * 8;
    float4 v0 = *(float4*)(p);
    float4 v1 = *(float4*)(p + 4);
    const float scale = 0.0625f;
    float m = fmaxf(fmaxf(fmaxf(v0.x, v0.y), fmaxf(v0.z, v0.w)),
                    fmaxf(fmaxf(v1.x, v1.y), fmaxf(v1.z, v1.w)));
#pragma unroll
    for (int off = 32; off >= 1; off >>= 1) m = fmaxf(m, __shfl_xor(m, off));
    v0.x = __expf((v0.x - m) * scale); v0.y = __expf((v0.y - m) * scale);
    v0.z = __expf((v0.z - m) * scale); v0.w = __expf((v0.w - m) * scale);
    v1.x = __expf((v1.x - m) * scale); v1.y = __expf((v1.y - m) * scale);
    v1.z = __expf((v1.z - m) * scale); v1.w = __expf((v1.w - m) * scale);
    float sum = v0.x + v0.y + v0.z + v0.w + v1.x + v1.y + v1.z + v1.w;
#pragma unroll
    for (int off = 32; off >= 1; off >>= 1) sum += __shfl_xor(sum, off);
    float inv = 1.f / sum;
    v0.x *= inv; v0.y *= inv; v0.z *= inv; v0.w *= inv;
    v1.x *= inv; v1.y *= inv; v1.z *= inv; v1.w *= inv;
    *(float4*)(p)     = v0;
    *(float4*)(p + 4) = v1;
}

// =====================================================================
// CRF emissions: fc[row][j] = dot(dec[row], crf_w[j]) + crf_b[j]
// =====================================================================
__global__ __launch_bounds__(192) void fc_crf_kernel(
    const float* __restrict__ dec, const float* __restrict__ W,
    const float* __restrict__ bias, float* __restrict__ out)
{
    __shared__ __align__(16) float Ws[NT][516];
    for (int i = threadIdx.x; i < NT*128; i += 192) {
        int j = i >> 7, c = (i & 127) * 4;
        *(float4*)&Ws[j][c] = *(const float4*)(W + (size_t)j*EE + c);
    }
    __syncthreads();
    const int t = threadIdx.x;
    const int rloc = t / NT;
    const int j = t - rloc * NT;
    const int row = blockIdx.x * 8 + rloc;
    const float4* a = (const float4*)(dec + (size_t)row * EE);
    float acc = 0.f;
#pragma unroll 4
    for (int i = 0; i < 128; ++i) {
        float4 x = a[i];
        float4 y = *(const float4*)&Ws[j][i*4];
        acc += x.x*y.x + x.y*y.y + x.z*y.z + x.w*y.w;
    }
    out[(size_t)row * NT + j] = acc + bias[j];
}

// =====================================================================
// CRF + seg, 64-thread blocks.  (Round-15: reverted to the round-11
// version — best measured 162.0 µs.  r10/r11/r14 = 163.8/162.0/189.5
// across ~130/~85/~100-instr step bodies → the phase is chain-latency
// bound at throttled clock; stop micro-optimizing it.)
// blocks 0..95: CRF tasks (forward / viterbi / numerator per batch).
// blocks >= 96: seg head, 8 rows per block.
// =====================================================================
__global__ __launch_bounds__(64, 1) void crf_seg_kernel(
    const float* __restrict__ fc, const int* __restrict__ labels,
    const float* __restrict__ start_t, const float* __restrict__ end_t,
    const float* __restrict__ trans, const float* __restrict__ dec,
    const float* __restrict__ ent_w, const float* __restrict__ ent_b,
    float* __restrict__ num, float* __restrict__ den,
    float* __restrict__ crf_out, float* __restrict__ segout)
{
    __shared__ __align__(16) float fc_lds[SS*NT];     // 48 KB (viterbi: reused as C1 scratch after recursion)
    __shared__ unsigned char hist[(SS-1)*NT];         // 12 KB  (C0)
    __shared__ unsigned char anchor[SS];              // backtrack anchors

    const int blk  = blockIdx.x;
    const int lane = threadIdx.x;

    if (blk >= 96) {
        // ---------------- segmentation head: 8 rows per block -----------
        const int row0 = (blk - 96) * 8;
        const float4* w0 = (const float4*)(ent_w);
        const float4* w1 = (const float4*)(ent_w + EE);
        const int i0 = lane * 2, i1 = lane * 2 + 1;
        const float4 u0 = w0[i0], u1 = w0[i1];
        const float4 q0 = w1[i0], q1 = w1[i1];
        const float eb0 = ent_b[0], eb1 = ent_b[1];
#pragma unroll 2
        for (int r = 0; r < 8; ++r) {
            const int row = row0 + r;
            const float4* a = (const float4*)(dec + (size_t)row * EE);
            float acc0 = 0.f, acc1 = 0.f;
            {
                float4 x = a[i0];
                acc0 += x.x*u0.x + x.y*u0.y + x.z*u0.z + x.w*u0.w;
                acc1 += x.x*q0.x + x.y*q0.y + x.z*q0.z + x.w*q0.w;
            }
            {
                float4 x = a[i1];
                acc0 += x.x*u1.x + x.y*u1.y + x.z*u1.z + x.w*u1.w;
                acc1 += x.x*q1.x + x.y*q1.y + x.z*q1.z + x.w*q1.w;
            }
#pragma unroll
            for (int off = 32; off >= 1; off >>= 1) {
                acc0 += __shfl_xor(acc0, off);
                acc1 += __shfl_xor(acc1, off);
            }
            if (lane == 0) {
                float l0 = acc0 + eb0;
                float l1 = acc1 + eb1;
                float m  = fmaxf(l0, l1);
                float lse = m + __logf(__expf(l0 - m) + __expf(l1 - m));
                segout[(size_t)row*2 + 0] = l0 - lse;
                segout[(size_t)row*2 + 1] = l1 - lse;
            }
        }
        return;
    }

    const int role = blk >> 5;          // 0=forward, 1=viterbi, 2=numerator
    const int b    = blk & 31;
    const float* fcb = fc + (size_t)b * SS * NT;

    if (role == 2) {
        // ---- numerator (one pass, already parallel; no LDS needed) ----
        float acc = 0.f;
        for (int s = 1 + lane; s < SS; s += 64) {
            int prev = labels[b*SS + s - 1];
            int cur  = labels[b*SS + s];
            acc += trans[prev*NT + cur] + fcb[(size_t)s*NT + cur];
        }
        if (lane == 0) {
            int l0 = labels[b*SS];
            acc += start_t[l0] + fcb[l0] + end_t[labels[b*SS + SS - 1]];
        }
#pragma unroll
        for (int off = 32; off >= 1; off >>= 1) acc += __shfl_xor(acc, off);
        if (lane == 0) num[b] = acc;
        return;
    }

    // ---- bulk-stage emissions into LDS: 12288 floats, 48 float4/lane ----
#pragma unroll
    for (int i = 0; i < SS*NT/256; ++i) {
        const int idx = i*256 + lane*4;
        *(float4*)&fc_lds[idx] = *(const float4*)(fcb + idx);
    }
    __syncthreads();

    // lane j<24 owns destination tag j
    const int j = (lane < NT) ? lane : 0;

    if (role == 0) {
        // ---- forward (log-normalizer) ----
        float sc = start_t[j] + fc_lds[j];
        float etr[NT];
#pragma unroll
        for (int i = 0; i < NT; ++i) etr[i] = __expf(trans[i*NT + j]);
        float em_next = fc_lds[NT + j];
        for (int s = 1; s < SS; ++s) {
            float em = em_next;
            int snx = (s + 1 < SS) ? s + 1 : s;
            em_next = fc_lds[snx * NT + j];          // LDS prefetch
            const float m  = __builtin_amdgcn_readfirstlane(sc);
            const float eo = __expf(sc - m);          // 1 exp per lane
            float a0 = 0.f, a1 = 0.f, a2 = 0.f, a3 = 0.f;
#pragma unroll
            for (int i = 0; i < NT; i += 4) {
                a0 = fmaf(rl(eo, i+0), etr[i+0], a0);
                a1 = fmaf(rl(eo, i+1), etr[i+1], a1);
                a2 = fmaf(rl(eo, i+2), etr[i+2], a2);
                a3 = fmaf(rl(eo, i+3), etr[i+3], a3);
            }
            sc = m + __logf((a0 + a1) + (a2 + a3)) + em;
        }
        float v = (lane < NT) ? sc + end_t[j] : -1e30f;
        float m2 = v;
#pragma unroll
        for (int off = 32; off >= 1; off >>= 1) m2 = fmaxf(m2, __shfl_xor(m2, off));
        float e = (lane < NT) ? __expf(v - m2) : 0.f;
#pragma unroll
        for (int off = 32; off >= 1; off >>= 1) e += __shfl_xor(e, off);
        if (lane == 0) den[b] = m2 + __logf(e);
    } else {
        // ---- viterbi: half-split candidate argmax (round-11 form) ----
        const int jj   = lane & 31;
        const int jc   = (jj < NT) ? jj : 0;
        const int half = lane >> 5;
        const int cb   = half * 12;          // candidate base index

        float trC[12];
#pragma unroll
        for (int ii = 0; ii < 12; ++ii) trC[ii] = trans[(cb + ii)*NT + jc];

        // sc lives (validly) in lanes 0..23; all broadcasts read there.
        float sc = start_t[jc] + fc_lds[jc];
        float em_next = fc_lds[NT + jc];
        for (int s = 1; s < SS; ++s) {
            float em = em_next;
            int snx = (s + 1 < SS) ? s + 1 : s;
            em_next = fc_lds[snx * NT + jc];
            float tv[12]; int ti[12];
#pragma unroll
            for (int ii = 0; ii < 12; ++ii) {
                tv[ii] = __shfl(sc, cb + ii) + trC[ii];
                ti[ii] = cb + ii;
            }
            // first-tie argmax tree over the 12 owned candidates
#pragma unroll
            for (int st = 1; st < 12; st <<= 1)
#pragma unroll
                for (int i = 0; i + st < 12; i += 2*st)
                    if (tv[i+st] > tv[i]) { tv[i] = tv[i+st]; ti[i] = ti[i+st]; }
            // combine halves: lower candidate index wins on tie
            float ov = __shfl_xor(tv[0], 32);
            int   oi = __shfl_xor(ti[0], 32);
            float bv = tv[0]; int bi2 = ti[0];
            if (ov > bv || (ov == bv && oi < bi2)) { bv = ov; bi2 = oi; }
            sc = bv + em;
            if (lane < NT) hist[(s-1)*NT + lane] = (unsigned char)bi2;
        }
        // final argmax over lanes (first-tie, lowest lane wins)
        float bv = (lane < NT) ? sc + end_t[jc] : -1e30f;
        int bi = (lane < NT) ? lane : NT;
#pragma unroll
        for (int off = 32; off >= 1; off >>= 1) {
            float ov = __shfl_xor(bv, off);
            int   oi = __shfl_xor(bi, off);
            if (ov > bv || (ov == bv && oi < bi)) { bv = ov; bi = oi; }
        }
        __syncthreads();   // drain LDS history writes

        // ---- backtrack, reach-2 composed ----
        // C0[h][t] = tag@h given tag@(h+1)=t,  h in 0..510  (== hist)
        // C1[h][t] = C0[h][C0[h+1][t]]         (odd h only; reach 2)
        unsigned char* C0 = hist;
        unsigned char* C1 = (unsigned char*)fc_lds;   // emissions dead now
        if (lane < 48) {
            const int t24 = (lane < 24) ? lane : lane - 24;
            const int h0c = (lane < 24) ? 1 : 3;
#pragma unroll 4
            for (int k = 0; k < 128; ++k) {
                int h = h0c + 4*k;
                if (h <= 509) {
                    int u = C0[(h+1)*NT + t24];
                    C1[h*NT + t24] = C0[h*NT + u];
                }
            }
        }
        __syncthreads();
        if (lane == 0) {
            int tg = bi;                 // tag @ 511
            anchor[SS-1] = (unsigned char)tg;
            for (int h = SS-3; h >= 1; h -= 2) {   // 509,507,...,1
                tg = C1[h*NT + tg];
                anchor[h] = (unsigned char)tg;
            }
        }
        __syncthreads();
        for (int s = lane; s < SS; s += 64) {
            int tag;
            if (s == SS-1)      tag = anchor[SS-1];
            else if (s & 1)     tag = anchor[s];
            else                tag = C0[s*NT + anchor[s+1]];
            crf_out[(size_t)b*SS + s] = (float)tag;
        }
    }
}

// =====================================================================
// Final scalar: -llh = -( sum_b(num[b]-den[b]) / 16384 )
// =====================================================================
__global__ __launch_bounds__(64) void llh_kernel(
    const float* __restrict__ num, const float* __restrict__ den,
    float* __restrict__ out)
{
    int t = threadIdx.x;
    float v = (t < BB) ? (num[t] - den[t]) : 0.f;
#pragma unroll
    for (int off = 32; off >= 1; off >>= 1) v += __shfl_xor(v, off);
    if (t == 0) out[(size_t)MR * 3] = -(v / (float)MR);
}

extern "C" void kernel_launch(void* const* d_in, const int* in_sizes, int n_in,
                              void* d_out, int out_size, void* d_ws, size_t ws_size,
                              hipStream_t stream) {
    const float* enc     = (const float*)d_in[0];
    const int*   labels  = (const int*)  d_in[1];
    // d_in[2] = mask (all ones by construction; unused)
    const float* Win     = (const float*)d_in[3];
    const float* bin     = (const float*)d_in[4];
    const float* Wout    = (const float*)d_in[5];
    const float* bout    = (const float*)d_in[6];
    const float* crf_w   = (const float*)d_in[7];
    const float* crf_b   = (const float*)d_in[8];
    const float* start_t = (const float*)d_in[9];
    const float* end_t   = (const float*)d_in[10];
    const float* trans   = (const float*)d_in[11];
    const float* ent_w   = (const float*)d_in[12];
    const float* ent_b   = (const float*)d_in[13];
    float* out = (float*)d_out;

    // Workspace layout — scores half (33.5 MB) aliases dec; scores are
    // dead before dec is written.
    float* ws   = (float*)d_ws;
    float* qkv  = ws;                                 // 16384*1536
    float* attn = qkv  + (size_t)MR * E3;             // 16384*512
    float* big  = attn + (size_t)MR * EE;             // 8,388,608 floats
    float* sch  = big;                                // scores half: 32*512*512
    float* dec  = big;                                // dec aliases scores
    float* fc   = big  + (size_t)MR * EE;             // 16384*24
    float* num  = fc   + (size_t)MR * NT;             // 32
    float* den  = num  + BB;                          // 32

    dim3 blk(256);
    // 1. qkv = enc @ Win^T + bin
    mfma_gemm<0><<<dim3(E3/128, MR/128, 1), blk, 0, stream>>>(
        enc, EE, 0, 0, 0,  Win, EE, 0, 0, 0,  bin,
        qkv, E3, 0, 0, 0,  EE, 0);
    // 2. attention in two z-passes of 32 (b,h) pairs each
    for (int p = 0; p < 2; ++p) {
        int zoff = p * 32;
        // scores[z][m][n] = Q[m].K[n]
        mfma_gemm<0><<<dim3(SS/128, SS/128, 32), blk, 0, stream>>>(
            qkv,      E3, (long)SS*E3, HDD, zoff,
            qkv + EE, E3, (long)SS*E3, HDD, zoff,
            nullptr,
            sch, SS, 2L*SS*SS, (long)SS*SS, 0,
            HDD, 0);
        softmax_rows<<<(32*SS)/4, blk, 0, stream>>>(sch);
        // attn[b,m,h*256+n] = sum_k P[z][m][k] V[b,k,h][n]
        mfma_gemm<1><<<dim3(HDD/128, SS/128, 32), blk, 0, stream>>>(
            sch, SS, 2L*SS*SS, (long)SS*SS, 0,
            qkv + 2*EE, E3, (long)SS*E3, HDD, zoff,
            nullptr,
            attn, EE, (long)SS*EE, HDD, zoff,
            SS, 0);
    }
    // 3. dec = relu(attn @ Wout^T + bout)   (overwrites scores region)
    mfma_gemm<0><<<dim3(EE/128, MR/128, 1), blk, 0, stream>>>(
        attn, EE, 0, 0, 0,  Wout, EE, 0, 0, 0,  bout,
        dec, EE, 0, 0, 0,  EE, 1);
    // 4. fc emissions
    fc_crf_kernel<<<MR/8, dim3(192), 0, stream>>>(dec, crf_w, crf_b, fc);
    // 5. CRF (forward+viterbi+numerator) + seg head (8 rows/block)
    crf_seg_kernel<<<96 + MR/8, dim3(64), 0, stream>>>(
        fc, labels, start_t, end_t, trans, dec, ent_w, ent_b,
        num, den, out, out + MR);
    // 6. -llh scalar -> d_out[49152]
    llh_kernel<<<1, 64, 0, stream>>>(num, den, out);
}

// Round 6
// 565.590 us; speedup vs baseline: 1.0868x; 1.0145x over previous
//
#include <hip/hip_runtime.h>

#define BB 32
#define SS 512
#define EE 512
#define NHH 2
#define HDD 256
#define E3 1536
#define NT 24
#define MR (BB*SS)   // 16384

typedef _Float16 half8  __attribute__((ext_vector_type(8)));
typedef _Float16 half4v __attribute__((ext_vector_type(4)));
typedef float    f32x4  __attribute__((ext_vector_type(4)));

// scalar (SGPR) lane broadcast — index MUST be wave-uniform.
__device__ __forceinline__ float rl(float v, int l) {
    return __int_as_float(__builtin_amdgcn_readlane(__float_as_int(v), l));
}

// =====================================================================
// fp32-accurate GEMM via fp16 3-product MFMA split (Ootomo).
// 128x128 block tile, 256 thr = 2x2 waves, 4x4 tiles of 16x16x32 f16.
// BN=0: B is row-major N x K (B^T form). BN=1: B is row-major K x N (V).
// Round-16: software pipeline — next tile's global loads issue right
// after the 2nd barrier so the 48-MFMA cluster hides their latency
// (T14 issue-early; matters most for PV at 1 block/CU).  BN=1 LDS
// writes vectorized (half4v along k, same addresses/values).
// =====================================================================
template<int BN>
__global__ __launch_bounds__(256) void mfma_gemm(
    const float* __restrict__ A, int lda, long sAhi, long sAlo, int zA,
    const float* __restrict__ B, int ldb, long sBhi, long sBlo, int zB,
    const float* __restrict__ bias,
    float* __restrict__ C, int ldc, long sChi, long sClo, int zC,
    int K, int relu)
{
    __shared__ __align__(16) _Float16 sAh[8*640];
    __shared__ __align__(16) _Float16 sAl[8*640];
    __shared__ __align__(16) _Float16 sBh[8*640];
    __shared__ __align__(16) _Float16 sBl[8*640];

    const int t = threadIdx.x;
    const int z = blockIdx.z;
    const int za = zA + z, zb = zB + z, zc = zC + z;
    const float* Ab = A + (size_t)(za>>1)*sAhi + (size_t)(za&1)*sAlo
                        + (size_t)blockIdx.y*128*lda;
    const float* Bb = B + (size_t)(zb>>1)*sBhi + (size_t)(zb&1)*sBlo
                        + (BN ? (size_t)blockIdx.x*128
                              : (size_t)blockIdx.x*128*ldb);

    const int wv = t >> 6, lane = t & 63;
    const int wm = wv >> 1, wn = wv & 1;
    const int lm = lane & 15, lq = lane >> 4;

    f32x4 acc[4][4];
#pragma unroll
    for (int i = 0; i < 4; ++i)
#pragma unroll
        for (int j = 0; j < 4; ++j) acc[i][j] = (f32x4){0.f,0.f,0.f,0.f};

    const int r8  = t >> 3;         // 0..31 (staging row base)
    const int kc  = (t & 7) * 4;    // 0..28 (staging k chunk)
    const int bnn4 = (t & 31) * 4;  // BN staging: n base (0..124)
    const int bnk4 = (t >> 5) * 4;  // BN staging: k base (0..28)

    auto loadA = [&](float4 g[4], int kk0) {
#pragma unroll
        for (int i = 0; i < 4; ++i)
            g[i] = *(const float4*)(Ab + (size_t)(r8 + 32*i)*lda + kk0 + kc);
    };
    auto loadB = [&](float4 g[4], int kk0) {
        if (BN) {
#pragma unroll
            for (int kk = 0; kk < 4; ++kk)
                g[kk] = *(const float4*)(Bb + (size_t)(kk0 + bnk4 + kk)*ldb + bnn4);
        } else {
#pragma unroll
            for (int i = 0; i < 4; ++i)
                g[i] = *(const float4*)(Bb + (size_t)(r8 + 32*i)*ldb + kk0 + kc);
        }
    };

    float4 ga[4], gb[4];
    loadA(ga, 0);
    loadB(gb, 0);

    for (int k0 = 0; k0 < K; k0 += 32) {
        __syncthreads();   // previous iteration's fragment reads complete
#pragma unroll
        for (int i = 0; i < 4; ++i) {
            const int row  = r8 + 32*i;
            const int base = (row >> 4)*640 + (row & 15)*40 + kc;
            float4 a = ga[i];
            _Float16 h0 = (_Float16)a.x, h1 = (_Float16)a.y,
                     h2 = (_Float16)a.z, h3 = (_Float16)a.w;
            _Float16 l0 = (_Float16)(a.x - (float)h0),
                     l1 = (_Float16)(a.y - (float)h1),
                     l2 = (_Float16)(a.z - (float)h2),
                     l3 = (_Float16)(a.w - (float)h3);
            *(half4v*)&sAh[base] = (half4v){h0,h1,h2,h3};
            *(half4v*)&sAl[base] = (half4v){l0,l1,l2,l3};
        }
        if (BN) {
            float vv[4][4];   // [kk][nn], all static indices
#pragma unroll
            for (int kk = 0; kk < 4; ++kk) {
                vv[kk][0] = gb[kk].x; vv[kk][1] = gb[kk].y;
                vv[kk][2] = gb[kk].z; vv[kk][3] = gb[kk].w;
            }
#pragma unroll
            for (int nn = 0; nn < 4; ++nn) {
                const int n = bnn4 + nn;
                half4v h, l;
#pragma unroll
                for (int kk = 0; kk < 4; ++kk) {
                    _Float16 hh = (_Float16)vv[kk][nn];
                    h[kk] = hh;
                    l[kk] = (_Float16)(vv[kk][nn] - (float)hh);
                }
                const int base = (n >> 4)*640 + (n & 15)*40 + bnk4;
                *(half4v*)&sBh[base] = h;
                *(half4v*)&sBl[base] = l;
            }
        } else {
#pragma unroll
            for (int i = 0; i < 4; ++i) {
                const int row  = r8 + 32*i;
                const int base = (row >> 4)*640 + (row & 15)*40 + kc;
                float4 b = gb[i];
                _Float16 h0 = (_Float16)b.x, h1 = (_Float16)b.y,
                         h2 = (_Float16)b.z, h3 = (_Float16)b.w;
                _Float16 l0 = (_Float16)(b.x - (float)h0),
                         l1 = (_Float16)(b.y - (float)h1),
                         l2 = (_Float16)(b.z - (float)h2),
                         l3 = (_Float16)(b.w - (float)h3);
                *(half4v*)&sBh[base] = (half4v){h0,h1,h2,h3};
                *(half4v*)&sBl[base] = (half4v){l0,l1,l2,l3};
            }
        }
        __syncthreads();

        // ---- issue next tile's loads NOW; MFMA cluster hides them ----
        float4 gan[4], gbn[4];
        const bool more = (k0 + 32 < K);
        if (more) {
            loadA(gan, k0 + 32);
            loadB(gbn, k0 + 32);
        }

        half8 bhf[4], blf[4];
#pragma unroll
        for (int j = 0; j < 4; ++j) {
            const int tb = (wn*4 + j)*640 + lm*40 + lq*8;
            bhf[j] = *(const half8*)&sBh[tb];
            blf[j] = *(const half8*)&sBl[tb];
        }
#pragma unroll
        for (int i = 0; i < 4; ++i) {
            const int ta = (wm*4 + i)*640 + lm*40 + lq*8;
            half8 ah = *(const half8*)&sAh[ta];
            half8 al = *(const half8*)&sAl[ta];
#pragma unroll
            for (int j = 0; j < 4; ++j) {
                acc[i][j] = __builtin_amdgcn_mfma_f32_16x16x32_f16(ah, bhf[j], acc[i][j], 0, 0, 0);
                acc[i][j] = __builtin_amdgcn_mfma_f32_16x16x32_f16(al, bhf[j], acc[i][j], 0, 0, 0);
                acc[i][j] = __builtin_amdgcn_mfma_f32_16x16x32_f16(ah, blf[j], acc[i][j], 0, 0, 0);
            }
        }

        if (more) {
#pragma unroll
            for (int i = 0; i < 4; ++i) { ga[i] = gan[i]; gb[i] = gbn[i]; }
        }
    }

    // epilogue: C/D layout col = lane&15, row = quad*4 + reg
    float* Cb = C + (size_t)(zc>>1)*sChi + (size_t)(zc&1)*sClo;
#pragma unroll
    for (int j = 0; j < 4; ++j) {
        const int col = blockIdx.x*128 + (wn*4 + j)*16 + lm;
        const float bj = bias ? bias[col] : 0.f;
#pragma unroll
        for (int i = 0; i < 4; ++i) {
            const int row0 = blockIdx.y*128 + (wm*4 + i)*16 + lq*4;
#pragma unroll
            for (int r = 0; r < 4; ++r) {
                float v = acc[i][j][r] + bj;
                if (relu) v = fmaxf(v, 0.f);
                Cb[(size_t)(row0 + r)*ldc + col] = v;
            }
        }
    }
}

// =====================================================================
// Row softmax over scores (in place, fully normalized).
// =====================================================================
__global__ __launch_bounds__(256) void softmax_rows(float* __restrict__ scores)
{
    const int w    = threadIdx.x >> 6;
    const int lane = threadIdx.x & 63;
    const size_t row = (size_t)blockIdx.x * 4 + w;
    float* p = scores + row * SS + lane * 8;
    float4 v0 = *(float4*)(p);
    float4 v1 = *(float4*)(p + 4);
    const float scale = 0.0625f;
    float m = fmaxf(fmaxf(fmaxf(v0.x, v0.y), fmaxf(v0.z, v0.w)),
                    fmaxf(fmaxf(v1.x, v1.y), fmaxf(v1.z, v1.w)));
#pragma unroll
    for (int off = 32; off >= 1; off >>= 1) m = fmaxf(m, __shfl_xor(m, off));
    v0.x = __expf((v0.x - m) * scale); v0.y = __expf((v0.y - m) * scale);
    v0.z = __expf((v0.z - m) * scale); v0.w = __expf((v0.w - m) * scale);
    v1.x = __expf((v1.x - m) * scale); v1.y = __expf((v1.y - m) * scale);
    v1.z = __expf((v1.z - m) * scale); v1.w = __expf((v1.w - m) * scale);
    float sum = v0.x + v0.y + v0.z + v0.w + v1.x + v1.y + v1.z + v1.w;
#pragma unroll
    for (int off = 32; off >= 1; off >>= 1) sum += __shfl_xor(sum, off);
    float inv = 1.f / sum;
    v0.x *= inv; v0.y *= inv; v0.z *= inv; v0.w *= inv;
    v1.x *= inv; v1.y *= inv; v1.z *= inv; v1.w *= inv;
    *(float4*)(p)     = v0;
    *(float4*)(p + 4) = v1;
}

// =====================================================================
// CRF emissions: fc[row][j] = dot(dec[row], crf_w[j]) + crf_b[j]
// =====================================================================
__global__ __launch_bounds__(192) void fc_crf_kernel(
    const float* __restrict__ dec, const float* __restrict__ W,
    const float* __restrict__ bias, float* __restrict__ out)
{
    __shared__ __align__(16) float Ws[NT][516];
    for (int i = threadIdx.x; i < NT*128; i += 192) {
        int j = i >> 7, c = (i & 127) * 4;
        *(float4*)&Ws[j][c] = *(const float4*)(W + (size_t)j*EE + c);
    }
    __syncthreads();
    const int t = threadIdx.x;
    const int rloc = t / NT;
    const int j = t - rloc * NT;
    const int row = blockIdx.x * 8 + rloc;
    const float4* a = (const float4*)(dec + (size_t)row * EE);
    float acc = 0.f;
#pragma unroll 4
    for (int i = 0; i < 128; ++i) {
        float4 x = a[i];
        float4 y = *(const float4*)&Ws[j][i*4];
        acc += x.x*y.x + x.y*y.y + x.z*y.z + x.w*y.w;
    }
    out[(size_t)row * NT + j] = acc + bias[j];
}

// =====================================================================
// CRF + seg, 64-thread blocks.  (r11 form — best measured 162.0 µs;
// the CRF recursions are chain-latency bound at throttled clock,
// r10/r11/r14 evidence; stop micro-optimizing.)
// blocks 0..95: CRF tasks (forward / viterbi / numerator per batch).
// blocks >= 96: seg head, 8 rows per block.
// =====================================================================
__global__ __launch_bounds__(64, 1) void crf_seg_kernel(
    const float* __restrict__ fc, const int* __restrict__ labels,
    const float* __restrict__ start_t, const float* __restrict__ end_t,
    const float* __restrict__ trans, const float* __restrict__ dec,
    const float* __restrict__ ent_w, const float* __restrict__ ent_b,
    float* __restrict__ num, float* __restrict__ den,
    float* __restrict__ crf_out, float* __restrict__ segout)
{
    __shared__ __align__(16) float fc_lds[SS*NT];     // 48 KB (viterbi: reused as C1 scratch after recursion)
    __shared__ unsigned char hist[(SS-1)*NT];         // 12 KB  (C0)
    __shared__ unsigned char anchor[SS];              // backtrack anchors

    const int blk  = blockIdx.x;
    const int lane = threadIdx.x;

    if (blk >= 96) {
        // ---------------- segmentation head: 8 rows per block -----------
        const int row0 = (blk - 96) * 8;
        const float4* w0 = (const float4*)(ent_w);
        const float4* w1 = (const float4*)(ent_w + EE);
        const int i0 = lane * 2, i1 = lane * 2 + 1;
        const float4 u0 = w0[i0], u1 = w0[i1];
        const float4 q0 = w1[i0], q1 = w1[i1];
        const float eb0 = ent_b[0], eb1 = ent_b[1];
#pragma unroll 2
        for (int r = 0; r < 8; ++r) {
            const int row = row0 + r;
            const float4* a = (const float4*)(dec + (size_t)row * EE);
            float acc0 = 0.f, acc1 = 0.f;
            {
                float4 x = a[i0];
                acc0 += x.x*u0.x + x.y*u0.y + x.z*u0.z + x.w*u0.w;
                acc1 += x.x*q0.x + x.y*q0.y + x.z*q0.z + x.w*q0.w;
            }
            {
                float4 x = a[i1];
                acc0 += x.x*u1.x + x.y*u1.y + x.z*u1.z + x.w*u1.w;
                acc1 += x.x*q1.x + x.y*q1.y + x.z*q1.z + x.w*q1.w;
            }
#pragma unroll
            for (int off = 32; off >= 1; off >>= 1) {
                acc0 += __shfl_xor(acc0, off);
                acc1 += __shfl_xor(acc1, off);
            }
            if (lane == 0) {
                float l0 = acc0 + eb0;
                float l1 = acc1 + eb1;
                float m  = fmaxf(l0, l1);
                float lse = m + __logf(__expf(l0 - m) + __expf(l1 - m));
                segout[(size_t)row*2 + 0] = l0 - lse;
                segout[(size_t)row*2 + 1] = l1 - lse;
            }
        }
        return;
    }

    const int role = blk >> 5;          // 0=forward, 1=viterbi, 2=numerator
    const int b    = blk & 31;
    const float* fcb = fc + (size_t)b * SS * NT;

    if (role == 2) {
        // ---- numerator (one pass, already parallel; no LDS needed) ----
        float acc = 0.f;
        for (int s = 1 + lane; s < SS; s += 64) {
            int prev = labels[b*SS + s - 1];
            int cur  = labels[b*SS + s];
            acc += trans[prev*NT + cur] + fcb[(size_t)s*NT + cur];
        }
        if (lane == 0) {
            int l0 = labels[b*SS];
            acc += start_t[l0] + fcb[l0] + end_t[labels[b*SS + SS - 1]];
        }
#pragma unroll
        for (int off = 32; off >= 1; off >>= 1) acc += __shfl_xor(acc, off);
        if (lane == 0) num[b] = acc;
        return;
    }

    // ---- bulk-stage emissions into LDS: 12288 floats, 48 float4/lane ----
#pragma unroll
    for (int i = 0; i < SS*NT/256; ++i) {
        const int idx = i*256 + lane*4;
        *(float4*)&fc_lds[idx] = *(const float4*)(fcb + idx);
    }
    __syncthreads();

    // lane j<24 owns destination tag j
    const int j = (lane < NT) ? lane : 0;

    if (role == 0) {
        // ---- forward (log-normalizer) ----
        float sc = start_t[j] + fc_lds[j];
        float etr[NT];
#pragma unroll
        for (int i = 0; i < NT; ++i) etr[i] = __expf(trans[i*NT + j]);
        float em_next = fc_lds[NT + j];
        for (int s = 1; s < SS; ++s) {
            float em = em_next;
            int snx = (s + 1 < SS) ? s + 1 : s;
            em_next = fc_lds[snx * NT + j];          // LDS prefetch
            const float m  = __builtin_amdgcn_readfirstlane(sc);
            const float eo = __expf(sc - m);          // 1 exp per lane
            float a0 = 0.f, a1 = 0.f, a2 = 0.f, a3 = 0.f;
#pragma unroll
            for (int i = 0; i < NT; i += 4) {
                a0 = fmaf(rl(eo, i+0), etr[i+0], a0);
                a1 = fmaf(rl(eo, i+1), etr[i+1], a1);
                a2 = fmaf(rl(eo, i+2), etr[i+2], a2);
                a3 = fmaf(rl(eo, i+3), etr[i+3], a3);
            }
            sc = m + __logf((a0 + a1) + (a2 + a3)) + em;
        }
        float v = (lane < NT) ? sc + end_t[j] : -1e30f;
        float m2 = v;
#pragma unroll
        for (int off = 32; off >= 1; off >>= 1) m2 = fmaxf(m2, __shfl_xor(m2, off));
        float e = (lane < NT) ? __expf(v - m2) : 0.f;
#pragma unroll
        for (int off = 32; off >= 1; off >>= 1) e += __shfl_xor(e, off);
        if (lane == 0) den[b] = m2 + __logf(e);
    } else {
        // ---- viterbi: half-split candidate argmax (round-11 form) ----
        const int jj   = lane & 31;
        const int jc   = (jj < NT) ? jj : 0;
        const int half = lane >> 5;
        const int cb   = half * 12;          // candidate base index

        float trC[12];
#pragma unroll
        for (int ii = 0; ii < 12; ++ii) trC[ii] = trans[(cb + ii)*NT + jc];

        // sc lives (validly) in lanes 0..23; all broadcasts read there.
        float sc = start_t[jc] + fc_lds[jc];
        float em_next = fc_lds[NT + jc];
        for (int s = 1; s < SS; ++s) {
            float em = em_next;
            int snx = (s + 1 < SS) ? s + 1 : s;
            em_next = fc_lds[snx * NT + jc];
            float tv[12]; int ti[12];
#pragma unroll
            for (int ii = 0; ii < 12; ++ii) {
                tv[ii] = __shfl(sc, cb + ii) + trC[ii];
                ti[ii] = cb + ii;
            }
            // first-tie argmax tree over the 12 owned candidates
#pragma unroll
            for (int st = 1; st < 12; st <<= 1)
#pragma unroll
                for (int i = 0; i + st < 12; i += 2*st)
                    if (tv[i+st] > tv[i]) { tv[i] = tv[i+st]; ti[i] = ti[i+st]; }
            // combine halves: lower candidate index wins on tie
            float ov = __shfl_xor(tv[0], 32);
            int   oi = __shfl_xor(ti[0], 32);
            float bv = tv[0]; int bi2 = ti[0];
            if (ov > bv || (ov == bv && oi < bi2)) { bv = ov; bi2 = oi; }
            sc = bv + em;
            if (lane < NT) hist[(s-1)*NT + lane] = (unsigned char)bi2;
        }
        // final argmax over lanes (first-tie, lowest lane wins)
        float bv = (lane < NT) ? sc + end_t[jc] : -1e30f;
        int bi = (lane < NT) ? lane : NT;
#pragma unroll
        for (int off = 32; off >= 1; off >>= 1) {
            float ov = __shfl_xor(bv, off);
            int   oi = __shfl_xor(bi, off);
            if (ov > bv || (ov == bv && oi < bi)) { bv = ov; bi = oi; }
        }
        __syncthreads();   // drain LDS history writes

        // ---- backtrack, reach-2 composed ----
        // C0[h][t] = tag@h given tag@(h+1)=t,  h in 0..510  (== hist)
        // C1[h][t] = C0[h][C0[h+1][t]]         (odd h only; reach 2)
        unsigned char* C0 = hist;
        unsigned char* C1 = (unsigned char*)fc_lds;   // emissions dead now
        if (lane < 48) {
            const int t24 = (lane < 24) ? lane : lane - 24;
            const int h0c = (lane < 24) ? 1 : 3;
#pragma unroll 4
            for (int k = 0; k < 128; ++k) {
                int h = h0c + 4*k;
                if (h <= 509) {
                    int u = C0[(h+1)*NT + t24];
                    C1[h*NT + t24] = C0[h*NT + u];
                }
            }
        }
        __syncthreads();
        if (lane == 0) {
            int tg = bi;                 // tag @ 511
            anchor[SS-1] = (unsigned char)tg;
            for (int h = SS-3; h >= 1; h -= 2) {   // 509,507,...,1
                tg = C1[h*NT + tg];
                anchor[h] = (unsigned char)tg;
            }
        }
        __syncthreads();
        for (int s = lane; s < SS; s += 64) {
            int tag;
            if (s == SS-1)      tag = anchor[SS-1];
            else if (s & 1)     tag = anchor[s];
            else                tag = C0[s*NT + anchor[s+1]];
            crf_out[(size_t)b*SS + s] = (float)tag;
        }
    }
}

// =====================================================================
// Final scalar: -llh = -( sum_b(num[b]-den[b]) / 16384 )
// =====================================================================
__global__ __launch_bounds__(64) void llh_kernel(
    const float* __restrict__ num, const float* __restrict__ den,
    float* __restrict__ out)
{
    int t = threadIdx.x;
    float v = (t < BB) ? (num[t] - den[t]) : 0.f;
#pragma unroll
    for (int off = 32; off >= 1; off >>= 1) v += __shfl_xor(v, off);
    if (t == 0) out[(size_t)MR * 3] = -(v / (float)MR);
}

extern "C" void kernel_launch(void* const* d_in, const int* in_sizes, int n_in,
                              void* d_out, int out_size, void* d_ws, size_t ws_size,
                              hipStream_t stream) {
    const float* enc     = (const float*)d_in[0];
    const int*   labels  = (const int*)  d_in[1];
    // d_in[2] = mask (all ones by construction; unused)
    const float* Win     = (const float*)d_in[3];
    const float* bin     = (const float*)d_in[4];
    const float* Wout    = (const float*)d_in[5];
    const float* bout    = (const float*)d_in[6];
    const float* crf_w   = (const float*)d_in[7];
    const float* crf_b   = (const float*)d_in[8];
    const float* start_t = (const float*)d_in[9];
    const float* end_t   = (const float*)d_in[10];
    const float* trans   = (const float*)d_in[11];
    const float* ent_w   = (const float*)d_in[12];
    const float* ent_b   = (const float*)d_in[13];
    float* out = (float*)d_out;

    // Workspace layout — scores half (33.5 MB) aliases dec; scores are
    // dead before dec is written.
    float* ws   = (float*)d_ws;
    float* qkv  = ws;                                 // 16384*1536
    float* attn = qkv  + (size_t)MR * E3;             // 16384*512
    float* big  = attn + (size_t)MR * EE;             // 8,388,608 floats
    float* sch  = big;                                // scores half: 32*512*512
    float* dec  = big;                                // dec aliases scores
    float* fc   = big  + (size_t)MR * EE;             // 16384*24
    float* num  = fc   + (size_t)MR * NT;             // 32
    float* den  = num  + BB;                          // 32

    dim3 blk(256);
    // 1. qkv = enc @ Win^T + bin
    mfma_gemm<0><<<dim3(E3/128, MR/128, 1), blk, 0, stream>>>(
        enc, EE, 0, 0, 0,  Win, EE, 0, 0, 0,  bin,
        qkv, E3, 0, 0, 0,  EE, 0);
    // 2. attention in two z-passes of 32 (b,h) pairs each
    for (int p = 0; p < 2; ++p) {
        int zoff = p * 32;
        // scores[z][m][n] = Q[m].K[n]
        mfma_gemm<0><<<dim3(SS/128, SS/128, 32), blk, 0, stream>>>(
            qkv,      E3, (long)SS*E3, HDD, zoff,
            qkv + EE, E3, (long)SS*E3, HDD, zoff,
            nullptr,
            sch, SS, 2L*SS*SS, (long)SS*SS, 0,
            HDD, 0);
        softmax_rows<<<(32*SS)/4, blk, 0, stream>>>(sch);
        // attn[b,m,h*256+n] = sum_k P[z][m][k] V[b,k,h][n]
        mfma_gemm<1><<<dim3(HDD/128, SS/128, 32), blk, 0, stream>>>(
            sch, SS, 2L*SS*SS, (long)SS*SS, 0,
            qkv + 2*EE, E3, (long)SS*E3, HDD, zoff,
            nullptr,
            attn, EE, (long)SS*EE, HDD, zoff,
            SS, 0);
    }
    // 3. dec = relu(attn @ Wout^T + bout)   (overwrites scores region)
    mfma_gemm<0><<<dim3(EE/128, MR/128, 1), blk, 0, stream>>>(
        attn, EE, 0, 0, 0,  Wout, EE, 0, 0, 0,  bout,
        dec, EE, 0, 0, 0,  EE, 1);
    // 4. fc emissions
    fc_crf_kernel<<<MR/8, dim3(192), 0, stream>>>(dec, crf_w, crf_b, fc);
    // 5. CRF (forward+viterbi+numerator) + seg head (8 rows/block)
    crf_seg_kernel<<<96 + MR/8, dim3(64), 0, stream>>>(
        fc, labels, start_t, end_t, trans, dec, ent_w, ent_b,
        num, den, out, out + MR);
    // 6. -llh scalar -> d_out[49152]
    llh_kernel<<<1, 64, 0, stream>>>(num, den, out);
}